// Round 1
// baseline (343.507 us; speedup 1.0000x reference)
//
#include <hip/hip_runtime.h>
#include <hip/hip_bf16.h>

using bf16 = __hip_bfloat16;
typedef __bf16 bf16x8 __attribute__((ext_vector_type(8)));
typedef float floatx4 __attribute__((ext_vector_type(4)));

// Problem dims
constexpr int BB = 4, SS = 2048, DIN = 512, DKK = 2048, DVV = 64;
constexpr int ROWS = BB * SS;          // 8192
constexpr int NQK = 2 * DKK;           // 4096 (q|k fused)

// ---- workspace layout (bytes) ----
constexpr size_t XB_OFF = 0;                                  // bf16 xb [8192][512]
constexpr size_t WT_OFF = XB_OFF + (size_t)ROWS * DIN * 2;    // bf16 wt [4096][512]  ([Wq|Wk]^T)
constexpr size_t VT_OFF = WT_OFF + (size_t)NQK * DIN * 2;     // bf16 vt [4][64][2048]
constexpr size_t QK_OFF = VT_OFF + (size_t)BB * DVV * SS * 2; // bf16 qk [8192][4096]; later aliased by P [4][2048][2048]
constexpr size_t SC_OFF = QK_OFF + (size_t)ROWS * NQK * 2;    // bf16 scores [4][2048][2048]
// total = ~109 MB

__device__ __forceinline__ void storeC(float* p, float v) { *p = v; }
__device__ __forceinline__ void storeC(bf16* p, float v) { *p = __float2bfloat16(v); }

__device__ __forceinline__ void async_copy16(const bf16* g, const unsigned short* l) {
    __builtin_amdgcn_global_load_lds((const __attribute__((address_space(1))) void*)g,
                                     (__attribute__((address_space(3))) void*)l, 16, 0, 0);
}

// ---------------- convert x -> bf16 (vectorized x4) ----------------
__global__ __launch_bounds__(256) void convert_x(const float* __restrict__ in,
                                                 bf16* __restrict__ out, int n4) {
    int i = blockIdx.x * 256 + threadIdx.x;
    if (i >= n4) return;
    float4 v = reinterpret_cast<const float4*>(in)[i];
    union { bf16 h[4]; ushort4 u; } cv;
    cv.h[0] = __float2bfloat16(v.x);
    cv.h[1] = __float2bfloat16(v.y);
    cv.h[2] = __float2bfloat16(v.z);
    cv.h[3] = __float2bfloat16(v.w);
    reinterpret_cast<ushort4*>(out)[i] = cv.u;
}

// ------------- transpose [Wq|Wk] (fp32 [512][2048] each) -> wt bf16 [4096][512] -------------
__global__ __launch_bounds__(256) void transpose_qk(const float* __restrict__ Wq,
                                                    const float* __restrict__ Wk,
                                                    bf16* __restrict__ wt) {
    int idx = blockIdx.x * 256 + threadIdx.x;   // over 4096*512
    int n = idx >> 9;                            // output row (0..4095)
    int k = idx & 511;                           // output col (0..511)
    float v = (n < DKK) ? Wq[(long long)k * DKK + n]
                        : Wk[(long long)k * DKK + (n - DKK)];
    wt[idx] = __float2bfloat16(v);
}

// ------------- vt[b][j][s] = sum_k x[b][s][k] * Wv[k][j]  (fp32 accumulate) -------------
__global__ __launch_bounds__(64) void compute_vt(const float* __restrict__ x,
                                                 const float* __restrict__ Wv,
                                                 bf16* __restrict__ vt) {
    int bs = blockIdx.x;                 // 0..8191
    int b = bs >> 11, s = bs & (SS - 1);
    __shared__ float xr[DIN];
    for (int i = threadIdx.x; i < DIN; i += 64) xr[i] = x[(long long)bs * DIN + i];
    __syncthreads();
    int j = threadIdx.x;                 // 0..63
    float acc = 0.f;
    #pragma unroll 8
    for (int k = 0; k < DIN; ++k) acc += xr[k] * Wv[k * DVV + j];
    vt[((long long)b * DVV + j) * SS + s] = __float2bfloat16(acc);
}

// ---------------- generic B^T GEMM: C[m][n] = sum_k A[m][k] * Bt[n][k] ----------------
// m97 structure: 16x16x32 bf16 MFMA, global_load_lds width=16, BK=32.
template <int BM, int BN, int MI, int NI, typename OutT, bool CSKIP>
__global__ __launch_bounds__(256) void gemm_bt(const bf16* __restrict__ A,
                                               const bf16* __restrict__ Bt,
                                               OutT* __restrict__ C,
                                               int K, int lda, int ldb, int ldc,
                                               long long sA, long long sB, long long sC) {
    if (CSKIP && (int)blockIdx.x > (int)blockIdx.y) return;  // fully-masked causal block
    constexpr int WROWS = BM / (MI * 16);
    constexpr int WCOLS = BN / (NI * 16);
    static_assert(WROWS * WCOLS == 4, "4 waves");
    constexpr int A_ISSUES = BM / 16;          // 1KB wave-issues for A tile
    constexpr int B_ISSUES = BN / 16;
    constexpr int T_ISSUES = A_ISSUES + B_ISSUES;

    __shared__ __align__(16) unsigned short As[BM * 32];
    __shared__ __align__(16) unsigned short Bs[BN * 32];

    const int tid = threadIdx.x;
    const int lane = tid & 63, wave = tid >> 6;
    const int bz = blockIdx.z;
    A += (long long)bz * sA;
    Bt += (long long)bz * sB;
    C += (long long)bz * sC;
    const long long m0 = (long long)blockIdx.y * BM;
    const long long n0 = (long long)blockIdx.x * BN;

    const int rowInIssue = lane >> 2;          // 16 rows per 1KB issue
    const int colInIssue = (lane & 3) * 8;     // bf16 elements within the 32-wide k tile

    const int wr = wave / WCOLS, wc = wave % WCOLS;
    const int wm0 = wr * MI * 16, wn0 = wc * NI * 16;
    const int l15 = lane & 15, quad = lane >> 4;

    floatx4 acc[MI][NI] = {};

    for (int k0 = 0; k0 < K; k0 += 32) {
        for (int t = wave; t < T_ISSUES; t += 4) {
            if (t < A_ISSUES) {
                int r = t * 16 + rowInIssue;
                async_copy16(A + (m0 + r) * (long long)lda + k0 + colInIssue, &As[t * 512]);
            } else {
                int tb = t - A_ISSUES;
                int r = tb * 16 + rowInIssue;
                async_copy16(Bt + (n0 + r) * (long long)ldb + k0 + colInIssue, &Bs[tb * 512]);
            }
        }
        __syncthreads();
        bf16x8 af[MI], bfr[NI];
        #pragma unroll
        for (int mi = 0; mi < MI; ++mi)
            af[mi] = *reinterpret_cast<const bf16x8*>(&As[(wm0 + mi * 16 + l15) * 32 + quad * 8]);
        #pragma unroll
        for (int ni = 0; ni < NI; ++ni)
            bfr[ni] = *reinterpret_cast<const bf16x8*>(&Bs[(wn0 + ni * 16 + l15) * 32 + quad * 8]);
        #pragma unroll
        for (int mi = 0; mi < MI; ++mi)
            #pragma unroll
            for (int ni = 0; ni < NI; ++ni)
                acc[mi][ni] = __builtin_amdgcn_mfma_f32_16x16x32_bf16(af[mi], bfr[ni], acc[mi][ni], 0, 0, 0);
        __syncthreads();
    }

    // epilogue: C/D layout col=lane&15, row=(lane>>4)*4+reg  [m89-verified]
    #pragma unroll
    for (int mi = 0; mi < MI; ++mi) {
        long long row0 = m0 + wm0 + mi * 16 + quad * 4;
        #pragma unroll
        for (int ni = 0; ni < NI; ++ni) {
            long long col = n0 + wn0 + ni * 16 + l15;
            #pragma unroll
            for (int r = 0; r < 4; ++r)
                storeC(&C[(row0 + r) * (long long)ldc + col], acc[mi][ni][r]);
        }
    }
}

// ---------------- causal row softmax: P = softmax(scores*scale) with col<=row mask ----------------
__global__ __launch_bounds__(256) void softmax_causal(const bf16* __restrict__ scores,
                                                      bf16* __restrict__ P, float scale) {
    int row = blockIdx.x;                // 0..8191
    int s = row & (SS - 1);
    const bf16* srow = scores + (long long)row * SS;
    bf16* prow = P + (long long)row * SS;
    int tid = threadIdx.x;
    int lane = tid & 63, wave = tid >> 6;

    float vals[8];
    float lmax = -INFINITY;
    #pragma unroll
    for (int it = 0; it < 8; ++it) {
        int i = tid + it * 256;
        float v = (i <= s) ? __bfloat162float(srow[i]) * scale : -INFINITY;
        vals[it] = v;
        lmax = fmaxf(lmax, v);
    }
    #pragma unroll
    for (int m = 32; m >= 1; m >>= 1) lmax = fmaxf(lmax, __shfl_xor(lmax, m));
    __shared__ float red[8];
    if (lane == 0) red[wave] = lmax;
    __syncthreads();
    float mx = fmaxf(fmaxf(red[0], red[1]), fmaxf(red[2], red[3]));

    float pv[8];
    float lsum = 0.f;
    #pragma unroll
    for (int it = 0; it < 8; ++it) {
        pv[it] = __expf(vals[it] - mx);   // masked -> exp(-inf)=0
        lsum += pv[it];
    }
    #pragma unroll
    for (int m = 32; m >= 1; m >>= 1) lsum += __shfl_xor(lsum, m);
    if (lane == 0) red[4 + wave] = lsum;
    __syncthreads();
    float rinv = 1.0f / (red[4] + red[5] + red[6] + red[7]);
    #pragma unroll
    for (int it = 0; it < 8; ++it) {
        int i = tid + it * 256;
        prow[i] = __float2bfloat16(pv[it] * rinv);
    }
}

extern "C" void kernel_launch(void* const* d_in, const int* in_sizes, int n_in,
                              void* d_out, int out_size, void* d_ws, size_t ws_size,
                              hipStream_t stream) {
    const float* x  = (const float*)d_in[0];
    const float* Wq = (const float*)d_in[1];
    const float* Wk = (const float*)d_in[2];
    const float* Wv = (const float*)d_in[3];
    float* out = (float*)d_out;

    char* w = (char*)d_ws;
    bf16* xb = (bf16*)(w + XB_OFF);
    bf16* wt = (bf16*)(w + WT_OFF);
    bf16* vt = (bf16*)(w + VT_OFF);
    bf16* qk = (bf16*)(w + QK_OFF);
    bf16* sc = (bf16*)(w + SC_OFF);
    bf16* P  = (bf16*)(w + QK_OFF);   // alias: qk dead after scores GEMM

    // 1. conversions
    convert_x<<<ROWS * DIN / 4 / 256, 256, 0, stream>>>(x, xb, ROWS * DIN / 4);
    transpose_qk<<<NQK * DIN / 256, 256, 0, stream>>>(Wq, Wk, wt);
    compute_vt<<<ROWS, 64, 0, stream>>>(x, Wv, vt);

    // 2. fused q|k projection: qk[8192][4096] = xb[8192][512] . wt^T
    gemm_bt<128, 128, 4, 4, bf16, false>
        <<<dim3(NQK / 128, ROWS / 128, 1), 256, 0, stream>>>(
            xb, wt, qk, DIN, DIN, DIN, NQK, 0, 0, 0);

    // 3. scores[b] = q[b] . k[b]^T (bf16 out, upper blocks skipped)
    gemm_bt<128, 128, 4, 4, bf16, true>
        <<<dim3(SS / 128, SS / 128, BB), 256, 0, stream>>>(
            qk, qk + DKK, sc, DKK, NQK, NQK, SS,
            (long long)SS * NQK, (long long)SS * NQK, (long long)SS * SS);

    // 4. causal softmax -> P (aliases qk region)
    softmax_causal<<<ROWS, 256, 0, stream>>>(sc, P, 0.022097086912079608f);  // 1/sqrt(2048)

    // 5. out[b] = P[b] . vt[b]^T  (fp32 out)
    gemm_bt<128, 64, 2, 4, float, false>
        <<<dim3(DVV / 64, SS / 128, BB), 256, 0, stream>>>(
            P, vt, out, SS, SS, SS, DVV,
            (long long)SS * SS, (long long)DVV * SS, (long long)SS * DVV);
}

// Round 2
// 312.046 us; speedup vs baseline: 1.1008x; 1.1008x over previous
//
#include <hip/hip_runtime.h>
#include <hip/hip_bf16.h>

using bf16 = __hip_bfloat16;
typedef __bf16 bf16x8 __attribute__((ext_vector_type(8)));
typedef float floatx4 __attribute__((ext_vector_type(4)));

// Problem dims
constexpr int BB = 4, SS = 2048, DIN = 512, DKK = 2048, DVV = 64;
constexpr int ROWS = BB * SS;          // 8192
constexpr int NQK = 2 * DKK;           // 4096 (q|k fused)

// ---- workspace layout (bytes) ----
constexpr size_t XB_OFF = 0;                                  // bf16 xb [8192][512]
constexpr size_t WT_OFF = XB_OFF + (size_t)ROWS * DIN * 2;    // bf16 wt [4096][512]  ([Wq|Wk]^T)
constexpr size_t VT_OFF = WT_OFF + (size_t)NQK * DIN * 2;     // bf16 vt [4][64][2048]
constexpr size_t QK_OFF = VT_OFF + (size_t)BB * DVV * SS * 2; // bf16 qk [8192][4096]; later aliased by P
constexpr size_t SC_OFF = QK_OFF + (size_t)ROWS * NQK * 2;    // bf16 scores [4][2048][2048]
// total = ~109 MB

__device__ __forceinline__ void storeC(float* p, float v) { *p = v; }
__device__ __forceinline__ void storeC(bf16* p, float v) { *p = __float2bfloat16(v); }

__device__ __forceinline__ void async_copy16(const bf16* g, const unsigned short* l) {
    __builtin_amdgcn_global_load_lds((const __attribute__((address_space(1))) void*)g,
                                     (__attribute__((address_space(3))) void*)l, 16, 0, 0);
}

// ---------------- convert x -> bf16 (vectorized x4) ----------------
__global__ __launch_bounds__(256) void convert_x(const float* __restrict__ in,
                                                 bf16* __restrict__ out, int n4) {
    int i = blockIdx.x * 256 + threadIdx.x;
    if (i >= n4) return;
    float4 v = reinterpret_cast<const float4*>(in)[i];
    union { bf16 h[4]; ushort4 u; } cv;
    cv.h[0] = __float2bfloat16(v.x);
    cv.h[1] = __float2bfloat16(v.y);
    cv.h[2] = __float2bfloat16(v.z);
    cv.h[3] = __float2bfloat16(v.w);
    reinterpret_cast<ushort4*>(out)[i] = cv.u;
}

// ------------- transpose [Wq|Wk] (fp32 [512][2048] each) -> wt bf16 [4096][512] -------------
__global__ __launch_bounds__(256) void transpose_qk(const float* __restrict__ Wq,
                                                    const float* __restrict__ Wk,
                                                    bf16* __restrict__ wt) {
    int idx = blockIdx.x * 256 + threadIdx.x;   // over 4096*512
    int n = idx >> 9;                            // output row (0..4095)
    int k = idx & 511;                           // output col (0..511)
    float v = (n < DKK) ? Wq[(long long)k * DKK + n]
                        : Wk[(long long)k * DKK + (n - DKK)];
    wt[idx] = __float2bfloat16(v);
}

// ------------- vt[b][j][s] = sum_k x[b][s][k] * Wv[k][j]  (fp32 accumulate) -------------
__global__ __launch_bounds__(64) void compute_vt(const float* __restrict__ x,
                                                 const float* __restrict__ Wv,
                                                 bf16* __restrict__ vt) {
    int bs = blockIdx.x;                 // 0..8191
    int b = bs >> 11, s = bs & (SS - 1);
    __shared__ float xr[DIN];
    for (int i = threadIdx.x; i < DIN; i += 64) xr[i] = x[(long long)bs * DIN + i];
    __syncthreads();
    int j = threadIdx.x;                 // 0..63
    float acc = 0.f;
    #pragma unroll 8
    for (int k = 0; k < DIN; ++k) acc += xr[k] * Wv[k * DVV + j];
    vt[((long long)b * DVV + j) * SS + s] = __float2bfloat16(acc);
}

// ---------------- zero-init d_out (re-poisoned 0xAA before every call) ----------------
__global__ __launch_bounds__(256) void zero_f4(float4* __restrict__ p, int n4) {
    int i = blockIdx.x * 256 + threadIdx.x;
    if (i < n4) p[i] = float4{0.f, 0.f, 0.f, 0.f};
}

// ---------------- generic B^T GEMM (BK=32, single-buffer): C[m][n] = sum_k A[m][k]*Bt[n][k] ----
// kchunks: split-K factor; blockIdx.z encodes (batch, kchunk). ATOMIC: atomicAdd epilogue.
template <int BM, int BN, int MI, int NI, typename OutT, bool ATOMIC>
__global__ __launch_bounds__(256) void gemm_bt(const bf16* __restrict__ A,
                                               const bf16* __restrict__ Bt,
                                               OutT* __restrict__ C,
                                               int K, int kchunks,
                                               int lda, int ldb, int ldc,
                                               long long sA, long long sB, long long sC) {
    constexpr int WCOLS = BN / (NI * 16);
    constexpr int A_ISSUES = BM / 16;          // 1KB wave-issues for A tile
    constexpr int B_ISSUES = BN / 16;
    constexpr int T_ISSUES = A_ISSUES + B_ISSUES;

    __shared__ __align__(16) unsigned short As[BM * 32];
    __shared__ __align__(16) unsigned short Bs[BN * 32];

    const int tid = threadIdx.x;
    const int lane = tid & 63, wave = tid >> 6;
    const int bz = blockIdx.z;
    const int b = bz / kchunks, kc = bz % kchunks;
    const int koff = kc * K;
    A += (long long)b * sA;
    Bt += (long long)b * sB;
    C += (long long)b * sC;
    const long long m0 = (long long)blockIdx.y * BM;
    const long long n0 = (long long)blockIdx.x * BN;

    const int rowInIssue = lane >> 2;          // 16 rows per 1KB issue
    const int colInIssue = (lane & 3) * 8;     // bf16 elements within the 32-wide k tile

    const int wr = wave / WCOLS, wc = wave % WCOLS;
    const int wm0 = wr * MI * 16, wn0 = wc * NI * 16;
    const int l15 = lane & 15, quad = lane >> 4;

    floatx4 acc[MI][NI] = {};

    for (int k0 = koff; k0 < koff + K; k0 += 32) {
        for (int t = wave; t < T_ISSUES; t += 4) {
            if (t < A_ISSUES) {
                int r = t * 16 + rowInIssue;
                async_copy16(A + (m0 + r) * (long long)lda + k0 + colInIssue, &As[t * 512]);
            } else {
                int tb = t - A_ISSUES;
                int r = tb * 16 + rowInIssue;
                async_copy16(Bt + (n0 + r) * (long long)ldb + k0 + colInIssue, &Bs[tb * 512]);
            }
        }
        __syncthreads();
        bf16x8 af[MI], bfr[NI];
        #pragma unroll
        for (int mi = 0; mi < MI; ++mi)
            af[mi] = *reinterpret_cast<const bf16x8*>(&As[(wm0 + mi * 16 + l15) * 32 + quad * 8]);
        #pragma unroll
        for (int ni = 0; ni < NI; ++ni)
            bfr[ni] = *reinterpret_cast<const bf16x8*>(&Bs[(wn0 + ni * 16 + l15) * 32 + quad * 8]);
        #pragma unroll
        for (int mi = 0; mi < MI; ++mi)
            #pragma unroll
            for (int ni = 0; ni < NI; ++ni)
                acc[mi][ni] = __builtin_amdgcn_mfma_f32_16x16x32_bf16(af[mi], bfr[ni], acc[mi][ni], 0, 0, 0);
        __syncthreads();
    }

    // epilogue: C/D layout col=lane&15, row=(lane>>4)*4+reg  [m89-verified]
    #pragma unroll
    for (int mi = 0; mi < MI; ++mi) {
        long long row0 = m0 + wm0 + mi * 16 + quad * 4;
        #pragma unroll
        for (int ni = 0; ni < NI; ++ni) {
            long long col = n0 + wn0 + ni * 16 + l15;
            #pragma unroll
            for (int r = 0; r < 4; ++r) {
                if constexpr (ATOMIC)
                    atomicAdd((float*)&C[(row0 + r) * (long long)ldc + col], acc[mi][ni][r]);
                else
                    storeC(&C[(row0 + r) * (long long)ldc + col], acc[mi][ni][r]);
            }
        }
    }
}

// ---------------- double-buffered causal scores GEMM (BK=64, one barrier/iter) ----------------
// Built for the grid-starved causal case: ~2 blocks/CU resident, so explicit dbuf is what
// hides the global_load_lds drain (the implicit wave-overlap argument of m99 doesn't apply).
template <int BM, int BN, int MI, int NI>
__global__ __launch_bounds__(256) void gemm_bt_db(const bf16* __restrict__ A,
                                                  const bf16* __restrict__ Bt,
                                                  bf16* __restrict__ C,
                                                  int K, int lda, int ldb, int ldc,
                                                  long long sA, long long sB, long long sC) {
    if ((int)blockIdx.x > (int)blockIdx.y) return;   // fully-masked causal block
    constexpr int BK = 64;
    constexpr int WCOLS = BN / (NI * 16);
    constexpr int A_ISS = BM / 8;                    // 1KB issue = 8 rows x 128B
    constexpr int B_ISS = BN / 8;
    constexpr int T_ISS = A_ISS + B_ISS;             // 32 -> 8 per wave

    __shared__ __align__(16) unsigned short As[2][BM * BK];
    __shared__ __align__(16) unsigned short Bs[2][BN * BK];

    const int tid = threadIdx.x;
    const int lane = tid & 63, wave = tid >> 6;
    const int bz = blockIdx.z;
    A += (long long)bz * sA;
    Bt += (long long)bz * sB;
    C += (long long)bz * sC;
    const long long m0 = (long long)blockIdx.y * BM;
    const long long n0 = (long long)blockIdx.x * BN;

    const int rIn = lane >> 3;                       // 0..7 (row within 8-row issue)
    const int cIn = (lane & 7) * 8;                  // bf16 element col within BK=64

    const int wr = wave / WCOLS, wc = wave % WCOLS;
    const int wm0 = wr * MI * 16, wn0 = wc * NI * 16;
    const int l15 = lane & 15, quad = lane >> 4;

    floatx4 acc[MI][NI] = {};

    auto issue = [&](int buf, int k0) {
        #pragma unroll
        for (int t0 = 0; t0 < T_ISS / 4; ++t0) {
            int t = t0 * 4 + wave;
            if (t < A_ISS)
                async_copy16(A + (m0 + t * 8 + rIn) * (long long)lda + k0 + cIn,
                             &As[buf][t * 512]);
            else {
                int tb = t - A_ISS;
                async_copy16(Bt + (n0 + tb * 8 + rIn) * (long long)ldb + k0 + cIn,
                             &Bs[buf][tb * 512]);
            }
        }
    };

    const int nIter = K / BK;
    issue(0, 0);
    __syncthreads();
    for (int it = 0; it < nIter; ++it) {
        const int cur = it & 1;
        if (it + 1 < nIter) issue(cur ^ 1, (it + 1) * BK);
        #pragma unroll
        for (int sk = 0; sk < BK / 32; ++sk) {
            bf16x8 af[MI], bfr[NI];
            #pragma unroll
            for (int mi = 0; mi < MI; ++mi)
                af[mi] = *reinterpret_cast<const bf16x8*>(
                    &As[cur][(wm0 + mi * 16 + l15) * BK + sk * 32 + quad * 8]);
            #pragma unroll
            for (int ni = 0; ni < NI; ++ni)
                bfr[ni] = *reinterpret_cast<const bf16x8*>(
                    &Bs[cur][(wn0 + ni * 16 + l15) * BK + sk * 32 + quad * 8]);
            #pragma unroll
            for (int mi = 0; mi < MI; ++mi)
                #pragma unroll
                for (int ni = 0; ni < NI; ++ni)
                    acc[mi][ni] = __builtin_amdgcn_mfma_f32_16x16x32_bf16(af[mi], bfr[ni],
                                                                          acc[mi][ni], 0, 0, 0);
        }
        __syncthreads();   // drains next-buffer loads (mostly covered by compute) + ds_reads
    }

    #pragma unroll
    for (int mi = 0; mi < MI; ++mi) {
        long long row0 = m0 + wm0 + mi * 16 + quad * 4;
        #pragma unroll
        for (int ni = 0; ni < NI; ++ni) {
            long long col = n0 + wn0 + ni * 16 + l15;
            #pragma unroll
            for (int r = 0; r < 4; ++r)
                C[(row0 + r) * (long long)ldc + col] = __float2bfloat16(acc[mi][ni][r]);
        }
    }
}

// ---------------- causal row softmax: P = softmax(scores*scale) with col<=row mask ----------------
__global__ __launch_bounds__(256) void softmax_causal(const bf16* __restrict__ scores,
                                                      bf16* __restrict__ P, float scale) {
    int row = blockIdx.x;                // 0..8191
    int s = row & (SS - 1);
    const bf16* srow = scores + (long long)row * SS;
    bf16* prow = P + (long long)row * SS;
    int tid = threadIdx.x;
    int lane = tid & 63, wave = tid >> 6;

    float vals[8];
    float lmax = -INFINITY;
    #pragma unroll
    for (int it = 0; it < 8; ++it) {
        int i = tid + it * 256;
        float v = (i <= s) ? __bfloat162float(srow[i]) * scale : -INFINITY;
        vals[it] = v;
        lmax = fmaxf(lmax, v);
    }
    #pragma unroll
    for (int m = 32; m >= 1; m >>= 1) lmax = fmaxf(lmax, __shfl_xor(lmax, m));
    __shared__ float red[8];
    if (lane == 0) red[wave] = lmax;
    __syncthreads();
    float mx = fmaxf(fmaxf(red[0], red[1]), fmaxf(red[2], red[3]));

    float pv[8];
    float lsum = 0.f;
    #pragma unroll
    for (int it = 0; it < 8; ++it) {
        pv[it] = __expf(vals[it] - mx);   // masked -> exp(-inf)=0
        lsum += pv[it];
    }
    #pragma unroll
    for (int m = 32; m >= 1; m >>= 1) lsum += __shfl_xor(lsum, m);
    if (lane == 0) red[4 + wave] = lsum;
    __syncthreads();
    float rinv = 1.0f / (red[4] + red[5] + red[6] + red[7]);
    #pragma unroll
    for (int it = 0; it < 8; ++it) {
        int i = tid + it * 256;
        prow[i] = __float2bfloat16(pv[it] * rinv);
    }
}

extern "C" void kernel_launch(void* const* d_in, const int* in_sizes, int n_in,
                              void* d_out, int out_size, void* d_ws, size_t ws_size,
                              hipStream_t stream) {
    const float* x  = (const float*)d_in[0];
    const float* Wq = (const float*)d_in[1];
    const float* Wk = (const float*)d_in[2];
    const float* Wv = (const float*)d_in[3];
    float* out = (float*)d_out;

    char* w = (char*)d_ws;
    bf16* xb = (bf16*)(w + XB_OFF);
    bf16* wt = (bf16*)(w + WT_OFF);
    bf16* vt = (bf16*)(w + VT_OFF);
    bf16* qk = (bf16*)(w + QK_OFF);
    bf16* sc = (bf16*)(w + SC_OFF);
    bf16* P  = (bf16*)(w + QK_OFF);   // alias: qk dead after scores GEMM

    // 1. conversions (+ zero d_out for the atomic split-K PV epilogue)
    convert_x<<<ROWS * DIN / 4 / 256, 256, 0, stream>>>(x, xb, ROWS * DIN / 4);
    transpose_qk<<<NQK * DIN / 256, 256, 0, stream>>>(Wq, Wk, wt);
    compute_vt<<<ROWS, 64, 0, stream>>>(x, Wv, vt);
    zero_f4<<<(ROWS * DVV / 4 + 255) / 256, 256, 0, stream>>>((float4*)out, ROWS * DVV / 4);

    // 2. fused q|k projection: qk[8192][4096] = xb[8192][512] . wt^T
    gemm_bt<128, 128, 4, 4, bf16, false>
        <<<dim3(NQK / 128, ROWS / 128, 1), 256, 0, stream>>>(
            xb, wt, qk, DIN, 1, DIN, DIN, NQK, 0, 0, 0);

    // 3. scores[b] = q[b] . k[b]^T (bf16 out, dbuf BK=64, causal blocks skipped)
    gemm_bt_db<128, 128, 4, 4>
        <<<dim3(SS / 128, SS / 128, BB), 256, 0, stream>>>(
            qk, qk + DKK, sc, DKK, NQK, NQK, SS,
            (long long)SS * NQK, (long long)SS * NQK, (long long)SS * SS);

    // 4. causal softmax -> P (aliases qk region)
    softmax_causal<<<ROWS, 256, 0, stream>>>(sc, P, 0.022097086912079608f);  // 1/sqrt(2048)

    // 5. out[b] = P[b] . vt[b]^T  (fp32, split-K 8, atomic accumulate)
    gemm_bt<128, 64, 2, 4, float, true>
        <<<dim3(DVV / 64, SS / 128, BB * 8), 256, 0, stream>>>(
            P, vt, out, SS / 8, 8, SS, SS, DVV,
            (long long)SS * SS, (long long)DVV * SS, (long long)SS * DVV);
}

// Round 3
// 276.014 us; speedup vs baseline: 1.2445x; 1.1305x over previous
//
#include <hip/hip_runtime.h>
#include <hip/hip_bf16.h>

using bf16 = __hip_bfloat16;
typedef __bf16 bf16x8 __attribute__((ext_vector_type(8)));
typedef float floatx4 __attribute__((ext_vector_type(4)));

// Problem dims
constexpr int BB = 4, SS = 2048, DIN = 512, DKK = 2048, DVV = 64;
constexpr int ROWS = BB * SS;          // 8192
constexpr int NQK = 2 * DKK;           // 4096 (q|k fused)

// ---- workspace layout (bytes) ----
constexpr size_t XB_OFF = 0;                                  // bf16 xb [8192][512]; later fp32 PV partials [4][4][2048][64] (8MB exactly)
constexpr size_t WT_OFF = XB_OFF + (size_t)ROWS * DIN * 2;    // bf16 wt [4096][512]  ([Wq|Wk]^T)
constexpr size_t VT_OFF = WT_OFF + (size_t)NQK * DIN * 2;     // bf16 vt [4][64][2048]
constexpr size_t QK_OFF = VT_OFF + (size_t)BB * DVV * SS * 2; // bf16 qk [8192][4096]; later aliased by P
constexpr size_t SC_OFF = QK_OFF + (size_t)ROWS * NQK * 2;    // bf16 scores [4][2048][2048]

__device__ __forceinline__ void storeC(float* p, float v) { *p = v; }
__device__ __forceinline__ void storeC(bf16* p, float v) { *p = __float2bfloat16(v); }

__device__ __forceinline__ void async_copy16(const bf16* g, const unsigned short* l) {
    __builtin_amdgcn_global_load_lds((const __attribute__((address_space(1))) void*)g,
                                     (__attribute__((address_space(3))) void*)l, 16, 0, 0);
}

// ---------------- convert x -> bf16 (vectorized x4) ----------------
__global__ __launch_bounds__(256) void convert_x(const float* __restrict__ in,
                                                 bf16* __restrict__ out, int n4) {
    int i = blockIdx.x * 256 + threadIdx.x;
    if (i >= n4) return;
    float4 v = reinterpret_cast<const float4*>(in)[i];
    union { bf16 h[4]; ushort4 u; } cv;
    cv.h[0] = __float2bfloat16(v.x);
    cv.h[1] = __float2bfloat16(v.y);
    cv.h[2] = __float2bfloat16(v.z);
    cv.h[3] = __float2bfloat16(v.w);
    reinterpret_cast<ushort4*>(out)[i] = cv.u;
}

// ------------- transpose [Wq|Wk] (fp32 [512][2048] each) -> wt bf16 [4096][512] -------------
__global__ __launch_bounds__(256) void transpose_qk(const float* __restrict__ Wq,
                                                    const float* __restrict__ Wk,
                                                    bf16* __restrict__ wt) {
    int idx = blockIdx.x * 256 + threadIdx.x;   // over 4096*512
    int n = idx >> 9;                            // output row (0..4095)
    int k = idx & 511;                           // output col (0..511)
    float v = (n < DKK) ? Wq[(long long)k * DKK + n]
                        : Wk[(long long)k * DKK + (n - DKK)];
    wt[idx] = __float2bfloat16(v);
}

// ------------- vt[b][j][s] = sum_k x[b][s][k] * Wv[k][j]  (fp32 accumulate) -------------
__global__ __launch_bounds__(64) void compute_vt(const float* __restrict__ x,
                                                 const float* __restrict__ Wv,
                                                 bf16* __restrict__ vt) {
    int bs = blockIdx.x;                 // 0..8191
    int b = bs >> 11, s = bs & (SS - 1);
    __shared__ float xr[DIN];
    for (int i = threadIdx.x; i < DIN; i += 64) xr[i] = x[(long long)bs * DIN + i];
    __syncthreads();
    int j = threadIdx.x;                 // 0..63
    float acc = 0.f;
    #pragma unroll 8
    for (int k = 0; k < DIN; ++k) acc += xr[k] * Wv[k * DVV + j];
    vt[((long long)b * DVV + j) * SS + s] = __float2bfloat16(acc);
}

// ---------------- generic B^T GEMM (BK=32, single-buffer): C[m][n] = sum_k A[m][k]*Bt[n][k] ----
// SPLIT: blockIdx.z = b*kchunks+kc; C += blockIdx.z*sC (per-chunk partials, no atomics);
//        causal chunk-skip: koff > m0+BM-1 -> acc stays 0, epilogue writes zeros.
template <int BM, int BN, int MI, int NI, typename OutT, bool SPLIT>
__global__ __launch_bounds__(256) void gemm_bt(const bf16* __restrict__ A,
                                               const bf16* __restrict__ Bt,
                                               OutT* __restrict__ C,
                                               int K, int kchunks,
                                               int lda, int ldb, int ldc,
                                               long long sA, long long sB, long long sC) {
    constexpr int WCOLS = BN / (NI * 16);
    constexpr int A_ISSUES = BM / 16;          // 1KB wave-issues for A tile
    constexpr int B_ISSUES = BN / 16;
    constexpr int T_ISSUES = A_ISSUES + B_ISSUES;

    __shared__ __align__(16) unsigned short As[BM * 32];
    __shared__ __align__(16) unsigned short Bs[BN * 32];

    const int tid = threadIdx.x;
    const int lane = tid & 63, wave = tid >> 6;
    const int bz = blockIdx.z;
    const int b = bz / kchunks, kc = bz % kchunks;
    const int koff = kc * K;
    A += (long long)b * sA;
    Bt += (long long)b * sB;
    if constexpr (SPLIT) C += (long long)bz * sC;
    else                 C += (long long)b * sC;
    const long long m0 = (long long)blockIdx.y * BM;
    const long long n0 = (long long)blockIdx.x * BN;

    const int rowInIssue = lane >> 2;          // 16 rows per 1KB issue
    const int colInIssue = (lane & 3) * 8;     // bf16 elements within the 32-wide k tile

    const int wr = wave / WCOLS, wc = wave % WCOLS;
    const int wm0 = wr * MI * 16, wn0 = wc * NI * 16;
    const int l15 = lane & 15, quad = lane >> 4;

    floatx4 acc[MI][NI] = {};

    const bool skip = SPLIT && (koff > m0 + BM - 1);   // fully-causal-masked k-chunk
    if (!skip)
    for (int k0 = koff; k0 < koff + K; k0 += 32) {
        for (int t = wave; t < T_ISSUES; t += 4) {
            if (t < A_ISSUES) {
                int r = t * 16 + rowInIssue;
                async_copy16(A + (m0 + r) * (long long)lda + k0 + colInIssue, &As[t * 512]);
            } else {
                int tb = t - A_ISSUES;
                int r = tb * 16 + rowInIssue;
                async_copy16(Bt + (n0 + r) * (long long)ldb + k0 + colInIssue, &Bs[tb * 512]);
            }
        }
        __syncthreads();
        bf16x8 af[MI], bfr[NI];
        #pragma unroll
        for (int mi = 0; mi < MI; ++mi)
            af[mi] = *reinterpret_cast<const bf16x8*>(&As[(wm0 + mi * 16 + l15) * 32 + quad * 8]);
        #pragma unroll
        for (int ni = 0; ni < NI; ++ni)
            bfr[ni] = *reinterpret_cast<const bf16x8*>(&Bs[(wn0 + ni * 16 + l15) * 32 + quad * 8]);
        #pragma unroll
        for (int mi = 0; mi < MI; ++mi)
            #pragma unroll
            for (int ni = 0; ni < NI; ++ni)
                acc[mi][ni] = __builtin_amdgcn_mfma_f32_16x16x32_bf16(af[mi], bfr[ni], acc[mi][ni], 0, 0, 0);
        __syncthreads();
    }

    // epilogue: C/D layout col=lane&15, row=(lane>>4)*4+reg  [m89-verified]
    #pragma unroll
    for (int mi = 0; mi < MI; ++mi) {
        long long row0 = m0 + wm0 + mi * 16 + quad * 4;
        #pragma unroll
        for (int ni = 0; ni < NI; ++ni) {
            long long col = n0 + wn0 + ni * 16 + l15;
            #pragma unroll
            for (int r = 0; r < 4; ++r)
                storeC(&C[(row0 + r) * (long long)ldc + col], acc[mi][ni][r]);
        }
    }
}

// ---------------- double-buffered causal scores GEMM (BK=64, XOR-swizzled LDS) ----------------
// Swizzle: global 16B chunk g of row r lives at LDS chunk g^(r&7). Applied on the GLOBAL side
// of global_load_lds (lane fetches permuted chunk of the same 128B segment -> coalescing kept,
// LDS dest stays lane-contiguous as the DMA requires). Read: chunk=(sk*4+quad)^(l15&7) ->
// 16 lanes hit 8 distinct 4-bank groups = 2 lanes/bank = conflict-free (m136).
template <int BM, int BN, int MI, int NI>
__global__ __launch_bounds__(256) void gemm_bt_db(const bf16* __restrict__ A,
                                                  const bf16* __restrict__ Bt,
                                                  bf16* __restrict__ C,
                                                  int K, int lda, int ldb, int ldc,
                                                  long long sA, long long sB, long long sC) {
    if ((int)blockIdx.x > (int)blockIdx.y) return;   // fully-masked causal block
    constexpr int BK = 64;
    constexpr int WCOLS = BN / (NI * 16);
    constexpr int A_ISS = BM / 8;                    // 1KB issue = 8 rows x 128B
    constexpr int B_ISS = BN / 8;
    constexpr int T_ISS = A_ISS + B_ISS;             // 32 -> 8 per wave

    __shared__ __align__(16) unsigned short As[2][BM * BK];
    __shared__ __align__(16) unsigned short Bs[2][BN * BK];

    const int tid = threadIdx.x;
    const int lane = tid & 63, wave = tid >> 6;
    const int bz = blockIdx.z;
    A += (long long)bz * sA;
    Bt += (long long)bz * sB;
    C += (long long)bz * sC;
    const long long m0 = (long long)blockIdx.y * BM;
    const long long n0 = (long long)blockIdx.x * BN;

    const int rIn = lane >> 3;                       // 0..7 (row within 8-row issue)
    const int cSwz = ((lane & 7) ^ rIn) * 8;         // swizzled global chunk (bf16 elements)

    const int wr = wave / WCOLS, wc = wave % WCOLS;
    const int wm0 = wr * MI * 16, wn0 = wc * NI * 16;
    const int l15 = lane & 15, quad = lane >> 4;
    const int sw7 = (l15 & 7);                       // read-side swizzle key

    floatx4 acc[MI][NI] = {};

    auto issue = [&](int buf, int k0) {
        #pragma unroll
        for (int t0 = 0; t0 < T_ISS / 4; ++t0) {
            int t = t0 * 4 + wave;
            if (t < A_ISS)
                async_copy16(A + (m0 + t * 8 + rIn) * (long long)lda + k0 + cSwz,
                             &As[buf][t * 512]);
            else {
                int tb = t - A_ISS;
                async_copy16(Bt + (n0 + tb * 8 + rIn) * (long long)ldb + k0 + cSwz,
                             &Bs[buf][tb * 512]);
            }
        }
    };

    const int nIter = K / BK;
    issue(0, 0);
    __syncthreads();
    for (int it = 0; it < nIter; ++it) {
        const int cur = it & 1;
        if (it + 1 < nIter) issue(cur ^ 1, (it + 1) * BK);
        #pragma unroll
        for (int sk = 0; sk < BK / 32; ++sk) {
            const int rchunk = ((sk << 2) | quad) ^ sw7;   // swizzled LDS chunk to read
            bf16x8 af[MI], bfr[NI];
            #pragma unroll
            for (int mi = 0; mi < MI; ++mi)
                af[mi] = *reinterpret_cast<const bf16x8*>(
                    &As[cur][(wm0 + mi * 16 + l15) * BK + rchunk * 8]);
            #pragma unroll
            for (int ni = 0; ni < NI; ++ni)
                bfr[ni] = *reinterpret_cast<const bf16x8*>(
                    &Bs[cur][(wn0 + ni * 16 + l15) * BK + rchunk * 8]);
            #pragma unroll
            for (int mi = 0; mi < MI; ++mi)
                #pragma unroll
                for (int ni = 0; ni < NI; ++ni)
                    acc[mi][ni] = __builtin_amdgcn_mfma_f32_16x16x32_bf16(af[mi], bfr[ni],
                                                                          acc[mi][ni], 0, 0, 0);
        }
        __syncthreads();
    }

    #pragma unroll
    for (int mi = 0; mi < MI; ++mi) {
        long long row0 = m0 + wm0 + mi * 16 + quad * 4;
        #pragma unroll
        for (int ni = 0; ni < NI; ++ni) {
            long long col = n0 + wn0 + ni * 16 + l15;
            #pragma unroll
            for (int r = 0; r < 4; ++r)
                C[(row0 + r) * (long long)ldc + col] = __float2bfloat16(acc[mi][ni][r]);
        }
    }
}

// ---------------- causal row softmax (vectorized x8): P = softmax(scores*scale) ----------------
// Writes only cols < (s/512+1)*512 — PV skips k-chunks entirely above the diagonal.
__global__ __launch_bounds__(256) void softmax_causal(const bf16* __restrict__ scores,
                                                      bf16* __restrict__ P, float scale) {
    int row = blockIdx.x;                // 0..8191
    int s = row & (SS - 1);
    const bf16* srow = scores + (long long)row * SS;
    bf16* prow = P + (long long)row * SS;
    int tid = threadIdx.x;
    int lane = tid & 63, wave = tid >> 6;
    int i0 = tid * 8;

    union { uint4 q; unsigned short u[8]; } ld;
    ld.q = make_uint4(0u, 0u, 0u, 0u);
    if (i0 <= s) ld.q = *reinterpret_cast<const uint4*>(srow + i0);

    float vals[8];
    float lmax = -INFINITY;
    #pragma unroll
    for (int j = 0; j < 8; ++j) {
        float v = __uint_as_float((unsigned)ld.u[j] << 16) * scale;
        vals[j] = (i0 + j <= s) ? v : -INFINITY;
        lmax = fmaxf(lmax, vals[j]);
    }
    #pragma unroll
    for (int m = 32; m >= 1; m >>= 1) lmax = fmaxf(lmax, __shfl_xor(lmax, m));
    __shared__ float red[8];
    if (lane == 0) red[wave] = lmax;
    __syncthreads();
    float mx = fmaxf(fmaxf(red[0], red[1]), fmaxf(red[2], red[3]));

    float pv[8];
    float lsum = 0.f;
    #pragma unroll
    for (int j = 0; j < 8; ++j) {
        pv[j] = __expf(vals[j] - mx);   // masked -> exp(-inf)=0
        lsum += pv[j];
    }
    #pragma unroll
    for (int m = 32; m >= 1; m >>= 1) lsum += __shfl_xor(lsum, m);
    if (lane == 0) red[4 + wave] = lsum;
    __syncthreads();
    float rinv = 1.0f / (red[4] + red[5] + red[6] + red[7]);

    int needed = ((s >> 9) + 1) << 9;    // multiple of 512 -> uniform per thread
    if (i0 < needed) {
        union { uint4 q; bf16 h[8]; } st;
        #pragma unroll
        for (int j = 0; j < 8; ++j) st.h[j] = __float2bfloat16(pv[j] * rinv);
        *reinterpret_cast<uint4*>(prow + i0) = st.q;
    }
}

// ---------------- reduce PV split-K partials: out = sum_kc part[b][kc] ----------------
__global__ __launch_bounds__(256) void reduce_pv(const float4* __restrict__ part,
                                                 float4* __restrict__ out, int n4) {
    int i = blockIdx.x * 256 + threadIdx.x;
    if (i >= n4) return;
    int b = i >> 15;                      // / 32768 (per-batch float4 count)
    int r = i & 32767;
    const float4* p = part + (long long)b * 131072 + r;
    float4 a0 = p[0], a1 = p[32768], a2 = p[65536], a3 = p[98304];
    out[i] = float4{a0.x + a1.x + a2.x + a3.x, a0.y + a1.y + a2.y + a3.y,
                    a0.z + a1.z + a2.z + a3.z, a0.w + a1.w + a2.w + a3.w};
}

extern "C" void kernel_launch(void* const* d_in, const int* in_sizes, int n_in,
                              void* d_out, int out_size, void* d_ws, size_t ws_size,
                              hipStream_t stream) {
    const float* x  = (const float*)d_in[0];
    const float* Wq = (const float*)d_in[1];
    const float* Wk = (const float*)d_in[2];
    const float* Wv = (const float*)d_in[3];
    float* out = (float*)d_out;

    char* w = (char*)d_ws;
    bf16* xb = (bf16*)(w + XB_OFF);
    bf16* wt = (bf16*)(w + WT_OFF);
    bf16* vt = (bf16*)(w + VT_OFF);
    bf16* qk = (bf16*)(w + QK_OFF);
    bf16* sc = (bf16*)(w + SC_OFF);
    bf16* P  = (bf16*)(w + QK_OFF);     // alias: qk dead after scores GEMM
    float* part = (float*)(w + XB_OFF); // alias: xb dead after projection (8MB = [4][4][2048][64] fp32)

    // 1. conversions
    convert_x<<<ROWS * DIN / 4 / 256, 256, 0, stream>>>(x, xb, ROWS * DIN / 4);
    transpose_qk<<<NQK * DIN / 256, 256, 0, stream>>>(Wq, Wk, wt);
    compute_vt<<<ROWS, 64, 0, stream>>>(x, Wv, vt);

    // 2. fused q|k projection: qk[8192][4096] = xb[8192][512] . wt^T
    gemm_bt<128, 128, 4, 4, bf16, false>
        <<<dim3(NQK / 128, ROWS / 128, 1), 256, 0, stream>>>(
            xb, wt, qk, DIN, 1, DIN, DIN, NQK, 0, 0, 0);

    // 3. scores[b] = q[b] . k[b]^T (bf16 out, dbuf BK=64, swizzled, causal blocks skipped)
    gemm_bt_db<128, 128, 4, 4>
        <<<dim3(SS / 128, SS / 128, BB), 256, 0, stream>>>(
            qk, qk + DKK, sc, DKK, NQK, NQK, SS,
            (long long)SS * NQK, (long long)SS * NQK, (long long)SS * SS);

    // 4. causal softmax -> P (aliases qk region)
    softmax_causal<<<ROWS, 256, 0, stream>>>(sc, P, 0.022097086912079608f);  // 1/sqrt(2048)

    // 5. out[b] = P[b] . vt[b]^T  (fp32 split-K 4 partials, causal chunk-skip, no atomics)
    gemm_bt<128, 64, 2, 4, float, true>
        <<<dim3(DVV / 64, SS / 128, BB * 4), 256, 0, stream>>>(
            P, vt, part, SS / 4, 4, SS, SS, DVV,
            (long long)SS * SS, (long long)DVV * SS, (long long)SS * DVV);

    // 6. out = sum_kc part
    reduce_pv<<<(ROWS * DVV / 4 + 255) / 256, 256, 0, stream>>>(
        (const float4*)part, (float4*)out, ROWS * DVV / 4);
}

// Round 5
// 249.715 us; speedup vs baseline: 1.3756x; 1.1053x over previous
//
#include <hip/hip_runtime.h>
#include <hip/hip_bf16.h>

using bf16 = __hip_bfloat16;
typedef __bf16 bf16x8 __attribute__((ext_vector_type(8)));
typedef float floatx4 __attribute__((ext_vector_type(4)));

// Problem dims
constexpr int BB = 4, SS = 2048, DIN = 512, DKK = 2048, DVV = 64;
constexpr int ROWS = BB * SS;          // 8192
constexpr int NQKV = 4224;             // q(2048) | k(2048) | v(64) | pad(64)

// ---- workspace layout (bytes) ----
constexpr size_t XB_OFF = 0;                                   // bf16 xb [8192][512]; later fp32 PV partials [4][4][2048][64]
constexpr size_t WT_OFF = XB_OFF + (size_t)ROWS * DIN * 2;     // bf16 wt [4224][512]  ([Wq|Wk|Wv|0]^T)
constexpr size_t VT_OFF = WT_OFF + (size_t)NQKV * DIN * 2;     // bf16 vt [4][64][2048]
constexpr size_t QK_OFF = VT_OFF + (size_t)BB * DVV * SS * 2;  // bf16 qkv [8192][4224]; later aliased by P [4][2048][2048]
constexpr size_t SC_OFF = QK_OFF + (size_t)ROWS * NQKV * 2;    // bf16 scores [4][2048][2048]

__device__ __forceinline__ void storeC(float* p, float v) { *p = v; }
__device__ __forceinline__ void storeC(bf16* p, float v) { *p = __float2bfloat16(v); }

__device__ __forceinline__ void async_copy16(const bf16* g, const unsigned short* l) {
    __builtin_amdgcn_global_load_lds((const __attribute__((address_space(1))) void*)g,
                                     (__attribute__((address_space(3))) void*)l, 16, 0, 0);
}

// ---------------- convert x -> bf16 (vectorized x4) ----------------
__global__ __launch_bounds__(256) void convert_x(const float* __restrict__ in,
                                                 bf16* __restrict__ out, int n4) {
    int i = blockIdx.x * 256 + threadIdx.x;
    if (i >= n4) return;
    float4 v = reinterpret_cast<const float4*>(in)[i];
    union { bf16 h[4]; ushort4 u; } cv;
    cv.h[0] = __float2bfloat16(v.x);
    cv.h[1] = __float2bfloat16(v.y);
    cv.h[2] = __float2bfloat16(v.z);
    cv.h[3] = __float2bfloat16(v.w);
    reinterpret_cast<ushort4*>(out)[i] = cv.u;
}

// ------------- LDS-tiled transpose: wt[4224][512] = [Wq|Wk|Wv|0]^T (both sides coalesced) ----
__global__ __launch_bounds__(256) void transpose_w(const float* __restrict__ Wq,
                                                   const float* __restrict__ Wk,
                                                   const float* __restrict__ Wv,
                                                   bf16* __restrict__ wt) {
    // tile: 32 n x 32 k; boundaries (2048/4096/4160) are multiples of 32 -> tile-uniform source
    int n0 = blockIdx.x * 32;               // 132 n-tiles (fixed: was `& 131`, a bogus mask)
    int k0 = blockIdx.y * 32;
    __shared__ float tile[32][33];
    int tid = threadIdx.x;
    int nn = tid & 31, kk8 = tid >> 5;      // 8 k-rows per pass, 4 passes
    const float* src; int col, ld;
    if (n0 < 2048)      { src = Wq; col = n0 + nn;        ld = 2048; }
    else if (n0 < 4096) { src = Wk; col = n0 - 2048 + nn; ld = 2048; }
    else if (n0 < 4160) { src = Wv; col = n0 - 4096 + nn; ld = 64;   }
    else                { src = nullptr; col = 0; ld = 0; }
    #pragma unroll
    for (int p = 0; p < 4; ++p) {
        int k = p * 8 + kk8;
        tile[k][nn] = src ? src[(long long)(k0 + k) * ld + col] : 0.f;
    }
    __syncthreads();
    int kk = tid & 31, nn8 = tid >> 5;
    #pragma unroll
    for (int p = 0; p < 4; ++p) {
        int n = p * 8 + nn8;
        wt[(long long)(n0 + n) * 512 + k0 + kk] = __float2bfloat16(tile[kk][n]);
    }
}

// ------------- vt[b][j][s] = qkv[b*2048+s][4096+j] (LDS-tiled 64x64) -------------
__global__ __launch_bounds__(256) void transpose_v(const bf16* __restrict__ qkv,
                                                   bf16* __restrict__ vt) {
    int rb = blockIdx.x;                  // 128 blocks of 64 s-rows
    int b = rb >> 5;
    int s0 = (rb & 31) * 64;
    __shared__ unsigned short tile[64][72];
    int tid = threadIdx.x;
    int rowInPass = tid >> 3;             // 0..31
    int c16 = (tid & 7) * 8;
    const bf16* src = qkv + ((long long)(b * SS + s0)) * NQKV + 4096;
    #pragma unroll
    for (int p = 0; p < 2; ++p) {
        int r = p * 32 + rowInPass;
        union { uint4 q; unsigned short u[8]; } ld;
        ld.q = *reinterpret_cast<const uint4*>(src + (long long)r * NQKV + c16);
        #pragma unroll
        for (int j = 0; j < 8; ++j) tile[r][c16 + j] = ld.u[j];
    }
    __syncthreads();
    int j = tid >> 2;                     // 0..63
    int sOff = (tid & 3) * 16;
    union { uint4 q[2]; unsigned short u[16]; } st;
    #pragma unroll
    for (int i = 0; i < 16; ++i) st.u[i] = tile[sOff + i][j];
    bf16* dst = vt + ((long long)b * DVV + j) * SS + s0 + sOff;
    *reinterpret_cast<uint4*>(dst) = st.q[0];
    *reinterpret_cast<uint4*>(dst + 8) = st.q[1];
}

// ---------------- single-buffer B^T GEMM (BK=32) — used for PV split-K ----------------
template <int BM, int BN, int MI, int NI, typename OutT>
__global__ __launch_bounds__(256) void gemm_bt(const bf16* __restrict__ A,
                                               const bf16* __restrict__ Bt,
                                               OutT* __restrict__ C,
                                               int K, int kchunks,
                                               int lda, int ldb, int ldc,
                                               long long sA, long long sB, long long sC) {
    constexpr int WCOLS = BN / (NI * 16);
    constexpr int A_ISSUES = BM / 16;
    constexpr int B_ISSUES = BN / 16;
    constexpr int T_ISSUES = A_ISSUES + B_ISSUES;

    __shared__ __align__(16) unsigned short As[BM * 32];
    __shared__ __align__(16) unsigned short Bs[BN * 32];

    const int tid = threadIdx.x;
    const int lane = tid & 63, wave = tid >> 6;
    const int bz = blockIdx.z;
    const int b = bz / kchunks, kc = bz % kchunks;
    const int koff = kc * K;
    A += (long long)b * sA;
    Bt += (long long)b * sB;
    C += (long long)bz * sC;              // per-chunk partial planes
    const long long m0 = (long long)blockIdx.y * BM;
    const long long n0 = (long long)blockIdx.x * BN;

    const int rowInIssue = lane >> 2;
    const int colInIssue = (lane & 3) * 8;

    const int wr = wave / WCOLS, wc = wave % WCOLS;
    const int wm0 = wr * MI * 16, wn0 = wc * NI * 16;
    const int l15 = lane & 15, quad = lane >> 4;

    floatx4 acc[MI][NI] = {};

    const bool skip = (koff > m0 + BM - 1);   // fully-causal-masked k-chunk
    if (!skip)
    for (int k0 = koff; k0 < koff + K; k0 += 32) {
        for (int t = wave; t < T_ISSUES; t += 4) {
            if (t < A_ISSUES) {
                int r = t * 16 + rowInIssue;
                async_copy16(A + (m0 + r) * (long long)lda + k0 + colInIssue, &As[t * 512]);
            } else {
                int tb = t - A_ISSUES;
                int r = tb * 16 + rowInIssue;
                async_copy16(Bt + (n0 + r) * (long long)ldb + k0 + colInIssue, &Bs[tb * 512]);
            }
        }
        __syncthreads();
        bf16x8 af[MI], bfr[NI];
        #pragma unroll
        for (int mi = 0; mi < MI; ++mi)
            af[mi] = *reinterpret_cast<const bf16x8*>(&As[(wm0 + mi * 16 + l15) * 32 + quad * 8]);
        #pragma unroll
        for (int ni = 0; ni < NI; ++ni)
            bfr[ni] = *reinterpret_cast<const bf16x8*>(&Bs[(wn0 + ni * 16 + l15) * 32 + quad * 8]);
        #pragma unroll
        for (int mi = 0; mi < MI; ++mi)
            #pragma unroll
            for (int ni = 0; ni < NI; ++ni)
                acc[mi][ni] = __builtin_amdgcn_mfma_f32_16x16x32_bf16(af[mi], bfr[ni], acc[mi][ni], 0, 0, 0);
        __syncthreads();
    }

    #pragma unroll
    for (int mi = 0; mi < MI; ++mi) {
        long long row0 = m0 + wm0 + mi * 16 + quad * 4;
        #pragma unroll
        for (int ni = 0; ni < NI; ++ni) {
            long long col = n0 + wn0 + ni * 16 + l15;
            #pragma unroll
            for (int r = 0; r < 4; ++r)
                storeC(&C[(row0 + r) * (long long)ldc + col], acc[mi][ni][r]);
        }
    }
}

// ---------------- double-buffered swizzled B^T GEMM (BK=64) ----------------
// CAUSAL: blockIdx.x is a compacted triangular index (no dead blocks, balanced).
// Swizzle (round-3 verified, conflicts=0): global chunk g of row r at LDS chunk g^(r&7);
// applied on the global side of global_load_lds, read back with chunk=(sk*4+quad)^(l15&7).
template <int BM, int BN, int MI, int NI, bool CAUSAL, typename OutT>
__global__ __launch_bounds__(256) void gemm_db(const bf16* __restrict__ A,
                                               const bf16* __restrict__ Bt,
                                               OutT* __restrict__ C,
                                               int K, int lda, int ldb, int ldc,
                                               long long sA, long long sB, long long sC) {
    constexpr int BK = 64;
    constexpr int WCOLS = BN / (NI * 16);
    constexpr int A_ISS = BM / 8;
    constexpr int B_ISS = BN / 8;
    constexpr int T_ISS = A_ISS + B_ISS;

    __shared__ __align__(16) unsigned short As[2][BM * BK];
    __shared__ __align__(16) unsigned short Bs[2][BN * BK];

    int bx, by;
    if constexpr (CAUSAL) {
        int t = blockIdx.x;
        int y = (int)((sqrtf(8.f * t + 1.f) - 1.f) * 0.5f);
        while ((y + 1) * (y + 2) / 2 <= t) ++y;
        while (y * (y + 1) / 2 > t) --y;
        bx = t - y * (y + 1) / 2;
        by = y;
    } else { bx = blockIdx.x; by = blockIdx.y; }

    const int tid = threadIdx.x;
    const int lane = tid & 63, wave = tid >> 6;
    const int bz = blockIdx.z;
    A += (long long)bz * sA;
    Bt += (long long)bz * sB;
    C += (long long)bz * sC;
    const long long m0 = (long long)by * BM;
    const long long n0 = (long long)bx * BN;

    const int rIn = lane >> 3;                       // row within 8-row issue
    const int cSwz = ((lane & 7) ^ rIn) * 8;         // swizzled global chunk (bf16 elems)

    const int wr = wave / WCOLS, wc = wave % WCOLS;
    const int wm0 = wr * MI * 16, wn0 = wc * NI * 16;
    const int l15 = lane & 15, quad = lane >> 4;
    const int sw7 = (l15 & 7);

    floatx4 acc[MI][NI] = {};

    auto issue = [&](int buf, int k0) {
        #pragma unroll
        for (int t0 = 0; t0 < T_ISS / 4; ++t0) {
            int t = t0 * 4 + wave;
            if (t < A_ISS)
                async_copy16(A + (m0 + t * 8 + rIn) * (long long)lda + k0 + cSwz,
                             &As[buf][t * 512]);
            else {
                int tb = t - A_ISS;
                async_copy16(Bt + (n0 + tb * 8 + rIn) * (long long)ldb + k0 + cSwz,
                             &Bs[buf][tb * 512]);
            }
        }
    };

    const int nIter = K / BK;
    issue(0, 0);
    __syncthreads();
    for (int it = 0; it < nIter; ++it) {
        const int cur = it & 1;
        if (it + 1 < nIter) issue(cur ^ 1, (it + 1) * BK);
        #pragma unroll
        for (int sk = 0; sk < BK / 32; ++sk) {
            const int rchunk = ((sk << 2) | quad) ^ sw7;
            bf16x8 af[MI], bfr[NI];
            #pragma unroll
            for (int mi = 0; mi < MI; ++mi)
                af[mi] = *reinterpret_cast<const bf16x8*>(
                    &As[cur][(wm0 + mi * 16 + l15) * BK + rchunk * 8]);
            #pragma unroll
            for (int ni = 0; ni < NI; ++ni)
                bfr[ni] = *reinterpret_cast<const bf16x8*>(
                    &Bs[cur][(wn0 + ni * 16 + l15) * BK + rchunk * 8]);
            #pragma unroll
            for (int mi = 0; mi < MI; ++mi)
                #pragma unroll
                for (int ni = 0; ni < NI; ++ni)
                    acc[mi][ni] = __builtin_amdgcn_mfma_f32_16x16x32_bf16(af[mi], bfr[ni],
                                                                          acc[mi][ni], 0, 0, 0);
        }
        __syncthreads();
    }

    #pragma unroll
    for (int mi = 0; mi < MI; ++mi) {
        long long row0 = m0 + wm0 + mi * 16 + quad * 4;
        #pragma unroll
        for (int ni = 0; ni < NI; ++ni) {
            long long col = n0 + wn0 + ni * 16 + l15;
            #pragma unroll
            for (int r = 0; r < 4; ++r)
                storeC(&C[(row0 + r) * (long long)ldc + col], acc[mi][ni][r]);
        }
    }
}

// ---------------- causal row softmax (vectorized x8) ----------------
__global__ __launch_bounds__(256) void softmax_causal(const bf16* __restrict__ scores,
                                                      bf16* __restrict__ P, float scale) {
    int row = blockIdx.x;
    int s = row & (SS - 1);
    const bf16* srow = scores + (long long)row * SS;
    bf16* prow = P + (long long)row * SS;
    int tid = threadIdx.x;
    int lane = tid & 63, wave = tid >> 6;
    int i0 = tid * 8;

    union { uint4 q; unsigned short u[8]; } ld;
    ld.q = make_uint4(0u, 0u, 0u, 0u);
    if (i0 <= s) ld.q = *reinterpret_cast<const uint4*>(srow + i0);

    float vals[8];
    float lmax = -INFINITY;
    #pragma unroll
    for (int j = 0; j < 8; ++j) {
        float v = __uint_as_float((unsigned)ld.u[j] << 16) * scale;
        vals[j] = (i0 + j <= s) ? v : -INFINITY;
        lmax = fmaxf(lmax, vals[j]);
    }
    #pragma unroll
    for (int m = 32; m >= 1; m >>= 1) lmax = fmaxf(lmax, __shfl_xor(lmax, m));
    __shared__ float red[8];
    if (lane == 0) red[wave] = lmax;
    __syncthreads();
    float mx = fmaxf(fmaxf(red[0], red[1]), fmaxf(red[2], red[3]));

    float pv[8];
    float lsum = 0.f;
    #pragma unroll
    for (int j = 0; j < 8; ++j) {
        pv[j] = __expf(vals[j] - mx);
        lsum += pv[j];
    }
    #pragma unroll
    for (int m = 32; m >= 1; m >>= 1) lsum += __shfl_xor(lsum, m);
    if (lane == 0) red[4 + wave] = lsum;
    __syncthreads();
    float rinv = 1.0f / (red[4] + red[5] + red[6] + red[7]);

    int needed = ((s >> 9) + 1) << 9;    // chunk-aligned: PV skips k-chunks above this
    if (i0 < needed) {
        union { uint4 q; bf16 h[8]; } st;
        #pragma unroll
        for (int j = 0; j < 8; ++j) st.h[j] = __float2bfloat16(pv[j] * rinv);
        *reinterpret_cast<uint4*>(prow + i0) = st.q;
    }
}

// ---------------- reduce PV split-K partials ----------------
__global__ __launch_bounds__(256) void reduce_pv(const float4* __restrict__ part,
                                                 float4* __restrict__ out, int n4) {
    int i = blockIdx.x * 256 + threadIdx.x;
    if (i >= n4) return;
    int b = i >> 15;
    int r = i & 32767;
    const float4* p = part + (long long)b * 131072 + r;
    float4 a0 = p[0], a1 = p[32768], a2 = p[65536], a3 = p[98304];
    out[i] = float4{a0.x + a1.x + a2.x + a3.x, a0.y + a1.y + a2.y + a3.y,
                    a0.z + a1.z + a2.z + a3.z, a0.w + a1.w + a2.w + a3.w};
}

extern "C" void kernel_launch(void* const* d_in, const int* in_sizes, int n_in,
                              void* d_out, int out_size, void* d_ws, size_t ws_size,
                              hipStream_t stream) {
    const float* x  = (const float*)d_in[0];
    const float* Wq = (const float*)d_in[1];
    const float* Wk = (const float*)d_in[2];
    const float* Wv = (const float*)d_in[3];
    float* out = (float*)d_out;

    char* w = (char*)d_ws;
    bf16* xb  = (bf16*)(w + XB_OFF);
    bf16* wt  = (bf16*)(w + WT_OFF);
    bf16* vt  = (bf16*)(w + VT_OFF);
    bf16* qkv = (bf16*)(w + QK_OFF);
    bf16* sc  = (bf16*)(w + SC_OFF);
    bf16* P   = (bf16*)(w + QK_OFF);    // alias: qkv dead after scores GEMM + v-transpose
    float* part = (float*)(w + XB_OFF); // alias: xb dead after projection

    // 1. conversions / transposes
    convert_x<<<ROWS * DIN / 4 / 256, 256, 0, stream>>>(x, xb, ROWS * DIN / 4);
    transpose_w<<<dim3(NQKV / 32, DIN / 32), 256, 0, stream>>>(Wq, Wk, Wv, wt);

    // 2. fused q|k|v projection: qkv[8192][4224] = xb . wt^T  (dbuf, swizzled)
    gemm_db<128, 128, 4, 4, false, bf16>
        <<<dim3(NQKV / 128, ROWS / 128, 1), 256, 0, stream>>>(
            xb, wt, qkv, DIN, DIN, DIN, NQKV, 0, 0, 0);

    // 2b. vt[b][j][s] from qkv v-columns
    transpose_v<<<ROWS / 64, 256, 0, stream>>>(qkv, vt);

    // 3. scores[b] = q[b].k[b]^T — compacted triangular grid (544 live blocks, balanced)
    gemm_db<128, 128, 4, 4, true, bf16>
        <<<dim3((SS / 128) * (SS / 128 + 1) / 2, 1, BB), 256, 0, stream>>>(
            qkv, qkv + DKK, sc, DKK, NQKV, NQKV, SS,
            (long long)SS * NQKV, (long long)SS * NQKV, (long long)SS * SS);

    // 4. causal softmax -> P (aliases qkv region)
    softmax_causal<<<ROWS, 256, 0, stream>>>(sc, P, 0.022097086912079608f);  // 1/sqrt(2048)

    // 5. out[b] = P[b].vt[b]^T  (fp32 split-K 4 partials, causal chunk-skip)
    gemm_bt<128, 64, 2, 4, float>
        <<<dim3(DVV / 64, SS / 128, BB * 4), 256, 0, stream>>>(
            P, vt, part, SS / 4, 4, SS, SS, DVV,
            (long long)SS * SS, (long long)DVV * SS, (long long)SS * DVV);

    // 6. out = sum_kc part
    reduce_pv<<<(ROWS * DVV / 4 + 255) / 256, 256, 0, stream>>>(
        (const float4*)part, (float4*)out, ROWS * DVV / 4);
}

// Round 6
// 237.983 us; speedup vs baseline: 1.4434x; 1.0493x over previous
//
#include <hip/hip_runtime.h>
#include <hip/hip_bf16.h>

using bf16 = __hip_bfloat16;
typedef __bf16 bf16x8 __attribute__((ext_vector_type(8)));
typedef float floatx4 __attribute__((ext_vector_type(4)));

// Problem dims
constexpr int BB = 4, SS = 2048, DIN = 512, DKK = 2048, DVV = 64;
constexpr int ROWS = BB * SS;          // 8192
constexpr int NQKV = 4224;             // q(2048) | k(2048) | v(64) | pad(64)

// ---- workspace layout (bytes) ----
constexpr size_t XB_OFF = 0;                                   // bf16 xb [8192][512]; later fp32 PV partials [4][4][2048][64]
constexpr size_t WT_OFF = XB_OFF + (size_t)ROWS * DIN * 2;     // bf16 wt [4224][512]  ([Wq|Wk|Wv|0]^T)
constexpr size_t VT_OFF = WT_OFF + (size_t)NQKV * DIN * 2;     // bf16 vt [4][64][2048]
constexpr size_t QK_OFF = VT_OFF + (size_t)BB * DVV * SS * 2;  // bf16 qkv [8192][4224]; later aliased by P [4][2048][2048]
constexpr size_t SC_OFF = QK_OFF + (size_t)ROWS * NQKV * 2;    // bf16 scores [4][2048][2048]

__device__ __forceinline__ void storeC(float* p, float v) { *p = v; }
__device__ __forceinline__ void storeC(bf16* p, float v) { *p = __float2bfloat16(v); }

__device__ __forceinline__ void async_copy16(const bf16* g, const unsigned short* l) {
    __builtin_amdgcn_global_load_lds((const __attribute__((address_space(1))) void*)g,
                                     (__attribute__((address_space(3))) void*)l, 16, 0, 0);
}

// ---------------- convert x -> bf16 (vectorized x4) ----------------
__global__ __launch_bounds__(256) void convert_x(const float* __restrict__ in,
                                                 bf16* __restrict__ out, int n4) {
    int i = blockIdx.x * 256 + threadIdx.x;
    if (i >= n4) return;
    float4 v = reinterpret_cast<const float4*>(in)[i];
    union { bf16 h[4]; ushort4 u; } cv;
    cv.h[0] = __float2bfloat16(v.x);
    cv.h[1] = __float2bfloat16(v.y);
    cv.h[2] = __float2bfloat16(v.z);
    cv.h[3] = __float2bfloat16(v.w);
    reinterpret_cast<ushort4*>(out)[i] = cv.u;
}

// ------------- LDS-tiled transpose: wt[4224][512] = [Wq|Wk|Wv|0]^T (both sides coalesced) ----
__global__ __launch_bounds__(256) void transpose_w(const float* __restrict__ Wq,
                                                   const float* __restrict__ Wk,
                                                   const float* __restrict__ Wv,
                                                   bf16* __restrict__ wt) {
    int n0 = blockIdx.x * 32;               // 132 n-tiles
    int k0 = blockIdx.y * 32;
    __shared__ float tile[32][33];
    int tid = threadIdx.x;
    int nn = tid & 31, kk8 = tid >> 5;      // 8 k-rows per pass, 4 passes
    const float* src; int col, ld;
    if (n0 < 2048)      { src = Wq; col = n0 + nn;        ld = 2048; }
    else if (n0 < 4096) { src = Wk; col = n0 - 2048 + nn; ld = 2048; }
    else if (n0 < 4160) { src = Wv; col = n0 - 4096 + nn; ld = 64;   }
    else                { src = nullptr; col = 0; ld = 0; }
    #pragma unroll
    for (int p = 0; p < 4; ++p) {
        int k = p * 8 + kk8;
        tile[k][nn] = src ? src[(long long)(k0 + k) * ld + col] : 0.f;
    }
    __syncthreads();
    int kk = tid & 31, nn8 = tid >> 5;
    #pragma unroll
    for (int p = 0; p < 4; ++p) {
        int n = p * 8 + nn8;
        wt[(long long)(n0 + n) * 512 + k0 + kk] = __float2bfloat16(tile[kk][n]);
    }
}

// ------------- vt[b][j][s] = qkv[b*2048+s][4096+j] (LDS-tiled 64x64) -------------
__global__ __launch_bounds__(256) void transpose_v(const bf16* __restrict__ qkv,
                                                   bf16* __restrict__ vt) {
    int rb = blockIdx.x;                  // 128 blocks of 64 s-rows
    int b = rb >> 5;
    int s0 = (rb & 31) * 64;
    __shared__ unsigned short tile[64][72];
    int tid = threadIdx.x;
    int rowInPass = tid >> 3;             // 0..31
    int c16 = (tid & 7) * 8;
    const bf16* src = qkv + ((long long)(b * SS + s0)) * NQKV + 4096;
    #pragma unroll
    for (int p = 0; p < 2; ++p) {
        int r = p * 32 + rowInPass;
        union { uint4 q; unsigned short u[8]; } ld;
        ld.q = *reinterpret_cast<const uint4*>(src + (long long)r * NQKV + c16);
        #pragma unroll
        for (int j = 0; j < 8; ++j) tile[r][c16 + j] = ld.u[j];
    }
    __syncthreads();
    int j = tid >> 2;                     // 0..63
    int sOff = (tid & 3) * 16;
    union { uint4 q[2]; unsigned short u[16]; } st;
    #pragma unroll
    for (int i = 0; i < 16; ++i) st.u[i] = tile[sOff + i][j];
    bf16* dst = vt + ((long long)b * DVV + j) * SS + s0 + sOff;
    *reinterpret_cast<uint4*>(dst) = st.q[0];
    *reinterpret_cast<uint4*>(dst + 8) = st.q[1];
}

// ---------------- single-buffer B^T GEMM (BK=32) — used for PV split-K ----------------
template <int BM, int BN, int MI, int NI, typename OutT>
__global__ __launch_bounds__(256) void gemm_bt(const bf16* __restrict__ A,
                                               const bf16* __restrict__ Bt,
                                               OutT* __restrict__ C,
                                               int K, int kchunks,
                                               int lda, int ldb, int ldc,
                                               long long sA, long long sB, long long sC) {
    constexpr int WCOLS = BN / (NI * 16);
    constexpr int A_ISSUES = BM / 16;
    constexpr int B_ISSUES = BN / 16;
    constexpr int T_ISSUES = A_ISSUES + B_ISSUES;

    __shared__ __align__(16) unsigned short As[BM * 32];
    __shared__ __align__(16) unsigned short Bs[BN * 32];

    const int tid = threadIdx.x;
    const int lane = tid & 63, wave = tid >> 6;
    const int bz = blockIdx.z;
    const int b = bz / kchunks, kc = bz % kchunks;
    const int koff = kc * K;
    A += (long long)b * sA;
    Bt += (long long)b * sB;
    C += (long long)bz * sC;              // per-chunk partial planes
    const long long m0 = (long long)blockIdx.y * BM;
    const long long n0 = (long long)blockIdx.x * BN;

    const int rowInIssue = lane >> 2;
    const int colInIssue = (lane & 3) * 8;

    const int wr = wave / WCOLS, wc = wave % WCOLS;
    const int wm0 = wr * MI * 16, wn0 = wc * NI * 16;
    const int l15 = lane & 15, quad = lane >> 4;

    floatx4 acc[MI][NI] = {};

    const bool skip = (koff > m0 + BM - 1);   // fully-causal-masked k-chunk
    if (!skip)
    for (int k0 = koff; k0 < koff + K; k0 += 32) {
        for (int t = wave; t < T_ISSUES; t += 4) {
            if (t < A_ISSUES) {
                int r = t * 16 + rowInIssue;
                async_copy16(A + (m0 + r) * (long long)lda + k0 + colInIssue, &As[t * 512]);
            } else {
                int tb = t - A_ISSUES;
                int r = tb * 16 + rowInIssue;
                async_copy16(Bt + (n0 + r) * (long long)ldb + k0 + colInIssue, &Bs[tb * 512]);
            }
        }
        __syncthreads();
        bf16x8 af[MI], bfr[NI];
        #pragma unroll
        for (int mi = 0; mi < MI; ++mi)
            af[mi] = *reinterpret_cast<const bf16x8*>(&As[(wm0 + mi * 16 + l15) * 32 + quad * 8]);
        #pragma unroll
        for (int ni = 0; ni < NI; ++ni)
            bfr[ni] = *reinterpret_cast<const bf16x8*>(&Bs[(wn0 + ni * 16 + l15) * 32 + quad * 8]);
        #pragma unroll
        for (int mi = 0; mi < MI; ++mi)
            #pragma unroll
            for (int ni = 0; ni < NI; ++ni)
                acc[mi][ni] = __builtin_amdgcn_mfma_f32_16x16x32_bf16(af[mi], bfr[ni], acc[mi][ni], 0, 0, 0);
        __syncthreads();
    }

    #pragma unroll
    for (int mi = 0; mi < MI; ++mi) {
        long long row0 = m0 + wm0 + mi * 16 + quad * 4;
        #pragma unroll
        for (int ni = 0; ni < NI; ++ni) {
            long long col = n0 + wn0 + ni * 16 + l15;
            #pragma unroll
            for (int r = 0; r < 4; ++r)
                storeC(&C[(row0 + r) * (long long)ldc + col], acc[mi][ni][r]);
        }
    }
}

// ---------------- 8-wave double-buffered swizzled B^T GEMM (128x128 tile, BK=64) ----------------
// 512 threads = 8 waves: 2 LDS-capped blocks/CU now carry 16 waves/CU (was 8) to hide
// global_load_lds miss latency. Wave-tile 32x64 (MI=2,NI=4). Swizzle as round 3 (conflicts=0).
// CAUSAL: rectangular fold — grid (17, 8, BB): row r pairs with row 15-r (lengths r+1 + 16-r = 17);
// no dead blocks, consecutive-x blocks share only 2 A-tile rows (keeps L2 locality).
template <bool CAUSAL, typename OutT>
__global__ __launch_bounds__(512) void gemm_db8(const bf16* __restrict__ A,
                                                const bf16* __restrict__ Bt,
                                                OutT* __restrict__ C,
                                                int K, int lda, int ldb, int ldc,
                                                long long sA, long long sB, long long sC) {
    constexpr int BM = 128, BN = 128, BK = 64;
    constexpr int MI = 2, NI = 4;

    __shared__ __align__(16) unsigned short As[2][BM * BK];
    __shared__ __align__(16) unsigned short Bs[2][BN * BK];

    int bx, by;
    if constexpr (CAUSAL) {
        int T2 = (int)gridDim.y * 2;          // tile-rows (16)
        int x = blockIdx.x, r = blockIdx.y;   // x in [0, T2/2+... (17)), r in [0,8)
        if (x <= r) { by = r; bx = x; }
        else        { by = T2 - 1 - r; bx = x - r - 1; }
    } else { bx = blockIdx.x; by = blockIdx.y; }

    const int tid = threadIdx.x;
    const int lane = tid & 63, wave = tid >> 6;      // wave 0..7
    const int bz = blockIdx.z;
    A += (long long)bz * sA;
    Bt += (long long)bz * sB;
    C += (long long)bz * sC;
    const long long m0 = (long long)by * BM;
    const long long n0 = (long long)bx * BN;

    const int rIn = lane >> 3;                       // row within 8-row issue
    const int cSwz = ((lane & 7) ^ rIn) * 8;         // swizzled global chunk (bf16 elems)

    const int wm0 = (wave >> 1) * 32, wn0 = (wave & 1) * 64;
    const int l15 = lane & 15, quad = lane >> 4;
    const int sw7 = (l15 & 7);

    floatx4 acc[MI][NI] = {};

    auto issue = [&](int buf, int k0) {
        #pragma unroll
        for (int t0 = 0; t0 < 4; ++t0) {
            int t = t0 * 8 + wave;                   // 0..31
            if (t < 16)
                async_copy16(A + (m0 + t * 8 + rIn) * (long long)lda + k0 + cSwz,
                             &As[buf][t * 512]);
            else {
                int tb = t - 16;
                async_copy16(Bt + (n0 + tb * 8 + rIn) * (long long)ldb + k0 + cSwz,
                             &Bs[buf][tb * 512]);
            }
        }
    };

    const int nIter = K / BK;
    issue(0, 0);
    __syncthreads();
    for (int it = 0; it < nIter; ++it) {
        const int cur = it & 1;
        if (it + 1 < nIter) issue(cur ^ 1, (it + 1) * BK);
        #pragma unroll
        for (int sk = 0; sk < BK / 32; ++sk) {
            const int rchunk = ((sk << 2) | quad) ^ sw7;
            bf16x8 af[MI], bfr[NI];
            #pragma unroll
            for (int mi = 0; mi < MI; ++mi)
                af[mi] = *reinterpret_cast<const bf16x8*>(
                    &As[cur][(wm0 + mi * 16 + l15) * BK + rchunk * 8]);
            #pragma unroll
            for (int ni = 0; ni < NI; ++ni)
                bfr[ni] = *reinterpret_cast<const bf16x8*>(
                    &Bs[cur][(wn0 + ni * 16 + l15) * BK + rchunk * 8]);
            #pragma unroll
            for (int mi = 0; mi < MI; ++mi)
                #pragma unroll
                for (int ni = 0; ni < NI; ++ni)
                    acc[mi][ni] = __builtin_amdgcn_mfma_f32_16x16x32_bf16(af[mi], bfr[ni],
                                                                          acc[mi][ni], 0, 0, 0);
        }
        __syncthreads();
    }

    #pragma unroll
    for (int mi = 0; mi < MI; ++mi) {
        long long row0 = m0 + wm0 + mi * 16 + quad * 4;
        #pragma unroll
        for (int ni = 0; ni < NI; ++ni) {
            long long col = n0 + wn0 + ni * 16 + l15;
            #pragma unroll
            for (int r = 0; r < 4; ++r)
                storeC(&C[(row0 + r) * (long long)ldc + col], acc[mi][ni][r]);
        }
    }
}

// ---------------- causal row softmax (vectorized x8) ----------------
__global__ __launch_bounds__(256) void softmax_causal(const bf16* __restrict__ scores,
                                                      bf16* __restrict__ P, float scale) {
    int row = blockIdx.x;
    int s = row & (SS - 1);
    const bf16* srow = scores + (long long)row * SS;
    bf16* prow = P + (long long)row * SS;
    int tid = threadIdx.x;
    int lane = tid & 63, wave = tid >> 6;
    int i0 = tid * 8;

    union { uint4 q; unsigned short u[8]; } ld;
    ld.q = make_uint4(0u, 0u, 0u, 0u);
    if (i0 <= s) ld.q = *reinterpret_cast<const uint4*>(srow + i0);

    float vals[8];
    float lmax = -INFINITY;
    #pragma unroll
    for (int j = 0; j < 8; ++j) {
        float v = __uint_as_float((unsigned)ld.u[j] << 16) * scale;
        vals[j] = (i0 + j <= s) ? v : -INFINITY;
        lmax = fmaxf(lmax, vals[j]);
    }
    #pragma unroll
    for (int m = 32; m >= 1; m >>= 1) lmax = fmaxf(lmax, __shfl_xor(lmax, m));
    __shared__ float red[8];
    if (lane == 0) red[wave] = lmax;
    __syncthreads();
    float mx = fmaxf(fmaxf(red[0], red[1]), fmaxf(red[2], red[3]));

    float pv[8];
    float lsum = 0.f;
    #pragma unroll
    for (int j = 0; j < 8; ++j) {
        pv[j] = __expf(vals[j] - mx);
        lsum += pv[j];
    }
    #pragma unroll
    for (int m = 32; m >= 1; m >>= 1) lsum += __shfl_xor(lsum, m);
    if (lane == 0) red[4 + wave] = lsum;
    __syncthreads();
    float rinv = 1.0f / (red[4] + red[5] + red[6] + red[7]);

    int needed = ((s >> 9) + 1) << 9;    // chunk-aligned: PV skips k-chunks above this
    if (i0 < needed) {
        union { uint4 q; bf16 h[8]; } st;
        #pragma unroll
        for (int j = 0; j < 8; ++j) st.h[j] = __float2bfloat16(pv[j] * rinv);
        *reinterpret_cast<uint4*>(prow + i0) = st.q;
    }
}

// ---------------- reduce PV split-K partials ----------------
__global__ __launch_bounds__(256) void reduce_pv(const float4* __restrict__ part,
                                                 float4* __restrict__ out, int n4) {
    int i = blockIdx.x * 256 + threadIdx.x;
    if (i >= n4) return;
    int b = i >> 15;
    int r = i & 32767;
    const float4* p = part + (long long)b * 131072 + r;
    float4 a0 = p[0], a1 = p[32768], a2 = p[65536], a3 = p[98304];
    out[i] = float4{a0.x + a1.x + a2.x + a3.x, a0.y + a1.y + a2.y + a3.y,
                    a0.z + a1.z + a2.z + a3.z, a0.w + a1.w + a2.w + a3.w};
}

extern "C" void kernel_launch(void* const* d_in, const int* in_sizes, int n_in,
                              void* d_out, int out_size, void* d_ws, size_t ws_size,
                              hipStream_t stream) {
    const float* x  = (const float*)d_in[0];
    const float* Wq = (const float*)d_in[1];
    const float* Wk = (const float*)d_in[2];
    const float* Wv = (const float*)d_in[3];
    float* out = (float*)d_out;

    char* w = (char*)d_ws;
    bf16* xb  = (bf16*)(w + XB_OFF);
    bf16* wt  = (bf16*)(w + WT_OFF);
    bf16* vt  = (bf16*)(w + VT_OFF);
    bf16* qkv = (bf16*)(w + QK_OFF);
    bf16* sc  = (bf16*)(w + SC_OFF);
    bf16* P   = (bf16*)(w + QK_OFF);    // alias: qkv dead after scores GEMM + v-transpose
    float* part = (float*)(w + XB_OFF); // alias: xb dead after projection

    // 1. conversions / transposes
    convert_x<<<ROWS * DIN / 4 / 256, 256, 0, stream>>>(x, xb, ROWS * DIN / 4);
    transpose_w<<<dim3(NQKV / 32, DIN / 32), 256, 0, stream>>>(Wq, Wk, Wv, wt);

    // 2. fused q|k|v projection: qkv[8192][4224] = xb . wt^T  (8-wave dbuf, swizzled)
    gemm_db8<false, bf16>
        <<<dim3(NQKV / 128, ROWS / 128, 1), 512, 0, stream>>>(
            xb, wt, qkv, DIN, DIN, DIN, NQKV, 0, 0, 0);

    // 2b. vt[b][j][s] from qkv v-columns
    transpose_v<<<ROWS / 64, 256, 0, stream>>>(qkv, vt);

    // 3. scores[b] = q[b].k[b]^T — rectangular causal fold (17x8 = 136 live blocks/batch)
    gemm_db8<true, bf16>
        <<<dim3(SS / 128 + 1, SS / 256, BB), 512, 0, stream>>>(
            qkv, qkv + DKK, sc, DKK, NQKV, NQKV, SS,
            (long long)SS * NQKV, (long long)SS * NQKV, (long long)SS * SS);

    // 4. causal softmax -> P (aliases qkv region)
    softmax_causal<<<ROWS, 256, 0, stream>>>(sc, P, 0.022097086912079608f);  // 1/sqrt(2048)

    // 5. out[b] = P[b].vt[b]^T  (fp32 split-K 4 partials, causal chunk-skip)
    gemm_bt<128, 64, 2, 4, float>
        <<<dim3(DVV / 64, SS / 128, BB * 4), 256, 0, stream>>>(
            P, vt, part, SS / 4, 4, SS, SS, DVV,
            (long long)SS * SS, (long long)DVV * SS, (long long)SS * DVV);

    // 6. out = sum_kc part
    reduce_pv<<<(ROWS * DVV / 4 + 255) / 256, 256, 0, stream>>>(
        (const float4*)part, (float4*)out, ROWS * DVV / 4);
}

// Round 7
// 223.968 us; speedup vs baseline: 1.5337x; 1.0626x over previous
//
#include <hip/hip_runtime.h>
#include <hip/hip_bf16.h>

using bf16 = __hip_bfloat16;
typedef __bf16 bf16x8 __attribute__((ext_vector_type(8)));
typedef float floatx4 __attribute__((ext_vector_type(4)));

// Problem dims
constexpr int BB = 4, SS = 2048, DIN = 512, DKK = 2048, DVV = 64;
constexpr int ROWS = BB * SS;          // 8192
constexpr int NQKV = 4224;             // q(2048) | k(2048) | v(64) | pad(64)

// ---- workspace layout (bytes) ----
constexpr size_t XB_OFF = 0;                                   // bf16 xb [8192][512]
constexpr size_t WT_OFF = XB_OFF + (size_t)ROWS * DIN * 2;     // bf16 wt [4224][512]; later fp32 stats [4][16][2048][2] (1.05MB of 4.3MB)
constexpr size_t VT_OFF = WT_OFF + (size_t)NQKV * DIN * 2;     // bf16 vt [4][64][2048]
constexpr size_t QK_OFF = VT_OFF + (size_t)BB * DVV * SS * 2;  // bf16 qkv [8192][4224]
constexpr size_t SC_OFF = QK_OFF + (size_t)ROWS * NQKV * 2;    // fp32 O' partials [4][16][2048][64] = 33.55 MB (same bytes as old scores)

__device__ __forceinline__ void storeC(float* p, float v) { *p = v; }
__device__ __forceinline__ void storeC(bf16* p, float v) { *p = __float2bfloat16(v); }

__device__ __forceinline__ void async_copy16(const bf16* g, const unsigned short* l) {
    __builtin_amdgcn_global_load_lds((const __attribute__((address_space(1))) void*)g,
                                     (__attribute__((address_space(3))) void*)l, 16, 0, 0);
}

// ---------------- convert x -> bf16 (vectorized x4) ----------------
__global__ __launch_bounds__(256) void convert_x(const float* __restrict__ in,
                                                 bf16* __restrict__ out, int n4) {
    int i = blockIdx.x * 256 + threadIdx.x;
    if (i >= n4) return;
    float4 v = reinterpret_cast<const float4*>(in)[i];
    union { bf16 h[4]; ushort4 u; } cv;
    cv.h[0] = __float2bfloat16(v.x);
    cv.h[1] = __float2bfloat16(v.y);
    cv.h[2] = __float2bfloat16(v.z);
    cv.h[3] = __float2bfloat16(v.w);
    reinterpret_cast<ushort4*>(out)[i] = cv.u;
}

// ------------- LDS-tiled transpose: wt[4224][512] = [Wq|Wk|Wv|0]^T -------------
__global__ __launch_bounds__(256) void transpose_w(const float* __restrict__ Wq,
                                                   const float* __restrict__ Wk,
                                                   const float* __restrict__ Wv,
                                                   bf16* __restrict__ wt) {
    int n0 = blockIdx.x * 32;               // 132 n-tiles
    int k0 = blockIdx.y * 32;
    __shared__ float tile[32][33];
    int tid = threadIdx.x;
    int nn = tid & 31, kk8 = tid >> 5;
    const float* src; int col, ld;
    if (n0 < 2048)      { src = Wq; col = n0 + nn;        ld = 2048; }
    else if (n0 < 4096) { src = Wk; col = n0 - 2048 + nn; ld = 2048; }
    else if (n0 < 4160) { src = Wv; col = n0 - 4096 + nn; ld = 64;   }
    else                { src = nullptr; col = 0; ld = 0; }
    #pragma unroll
    for (int p = 0; p < 4; ++p) {
        int k = p * 8 + kk8;
        tile[k][nn] = src ? src[(long long)(k0 + k) * ld + col] : 0.f;
    }
    __syncthreads();
    int kk = tid & 31, nn8 = tid >> 5;
    #pragma unroll
    for (int p = 0; p < 4; ++p) {
        int n = p * 8 + nn8;
        wt[(long long)(n0 + n) * 512 + k0 + kk] = __float2bfloat16(tile[kk][n]);
    }
}

// ------------- vt[b][j][s] = qkv[b*2048+s][4096+j] (LDS-tiled 64x64) -------------
__global__ __launch_bounds__(256) void transpose_v(const bf16* __restrict__ qkv,
                                                   bf16* __restrict__ vt) {
    int rb = blockIdx.x;                  // 128 blocks of 64 s-rows
    int b = rb >> 5;
    int s0 = (rb & 31) * 64;
    __shared__ unsigned short tile[64][72];
    int tid = threadIdx.x;
    int rowInPass = tid >> 3;
    int c16 = (tid & 7) * 8;
    const bf16* src = qkv + ((long long)(b * SS + s0)) * NQKV + 4096;
    #pragma unroll
    for (int p = 0; p < 2; ++p) {
        int r = p * 32 + rowInPass;
        union { uint4 q; unsigned short u[8]; } ld;
        ld.q = *reinterpret_cast<const uint4*>(src + (long long)r * NQKV + c16);
        #pragma unroll
        for (int j = 0; j < 8; ++j) tile[r][c16 + j] = ld.u[j];
    }
    __syncthreads();
    int j = tid >> 2;
    int sOff = (tid & 3) * 16;
    union { uint4 q[2]; unsigned short u[16]; } st;
    #pragma unroll
    for (int i = 0; i < 16; ++i) st.u[i] = tile[sOff + i][j];
    bf16* dst = vt + ((long long)b * DVV + j) * SS + s0 + sOff;
    *reinterpret_cast<uint4*>(dst) = st.q[0];
    *reinterpret_cast<uint4*>(dst + 8) = st.q[1];
}

// ---------------- 8-wave dbuf swizzled B^T GEMM (projection only) ----------------
template <typename OutT>
__global__ __launch_bounds__(512) void gemm_db8(const bf16* __restrict__ A,
                                                const bf16* __restrict__ Bt,
                                                OutT* __restrict__ C,
                                                int K, int lda, int ldb, int ldc) {
    constexpr int BK = 64;
    __shared__ __align__(16) unsigned short As[2][128 * BK];
    __shared__ __align__(16) unsigned short Bs[2][128 * BK];

    const int tid = threadIdx.x;
    const int lane = tid & 63, wave = tid >> 6;
    const long long m0 = (long long)blockIdx.y * 128;
    const long long n0 = (long long)blockIdx.x * 128;

    const int rIn = lane >> 3;
    const int cSwz = ((lane & 7) ^ rIn) * 8;
    const int wm0 = (wave >> 1) * 32, wn0 = (wave & 1) * 64;
    const int l15 = lane & 15, quad = lane >> 4;
    const int sw7 = l15 & 7;

    floatx4 acc[2][4] = {};

    auto issue = [&](int buf, int k0) {
        #pragma unroll
        for (int t0 = 0; t0 < 4; ++t0) {
            int t = t0 * 8 + wave;
            if (t < 16)
                async_copy16(A + (m0 + t * 8 + rIn) * (long long)lda + k0 + cSwz,
                             &As[buf][t * 512]);
            else
                async_copy16(Bt + (n0 + (t - 16) * 8 + rIn) * (long long)ldb + k0 + cSwz,
                             &Bs[buf][(t - 16) * 512]);
        }
    };

    const int nIter = K / BK;
    issue(0, 0);
    __syncthreads();
    for (int it = 0; it < nIter; ++it) {
        const int cur = it & 1;
        if (it + 1 < nIter) issue(cur ^ 1, (it + 1) * BK);
        #pragma unroll
        for (int sk = 0; sk < 2; ++sk) {
            const int rchunk = ((sk << 2) | quad) ^ sw7;
            bf16x8 af[2], bfr[4];
            #pragma unroll
            for (int mi = 0; mi < 2; ++mi)
                af[mi] = *reinterpret_cast<const bf16x8*>(
                    &As[cur][(wm0 + mi * 16 + l15) * BK + rchunk * 8]);
            #pragma unroll
            for (int ni = 0; ni < 4; ++ni)
                bfr[ni] = *reinterpret_cast<const bf16x8*>(
                    &Bs[cur][(wn0 + ni * 16 + l15) * BK + rchunk * 8]);
            #pragma unroll
            for (int mi = 0; mi < 2; ++mi)
                #pragma unroll
                for (int ni = 0; ni < 4; ++ni)
                    acc[mi][ni] = __builtin_amdgcn_mfma_f32_16x16x32_bf16(af[mi], bfr[ni],
                                                                          acc[mi][ni], 0, 0, 0);
        }
        __syncthreads();
    }

    #pragma unroll
    for (int mi = 0; mi < 2; ++mi) {
        long long row0 = m0 + wm0 + mi * 16 + quad * 4;
        #pragma unroll
        for (int ni = 0; ni < 4; ++ni) {
            long long col = n0 + wn0 + ni * 16 + l15;
            #pragma unroll
            for (int r = 0; r < 4; ++r)
                storeC(&C[(row0 + r) * (long long)ldc + col], acc[mi][ni][r]);
        }
    }
}

// ---------------- fused causal attention tile: S=QK^T -> per-tile softmax -> O'=P~V ----------------
// One block per (q-tile 128, k-tile 128, batch), rectangular fold grid (17,8,BB).
// Writes unnormalized O' (fp32) + per-row (m,l) stats; combine() merges across k-tiles.
// P~ C-layout -> A-layout via padded LDS (stride 136 bf16) [m120 pattern].
__global__ __launch_bounds__(512) void attn_fused(const bf16* __restrict__ qkv,
                                                  const bf16* __restrict__ vt,
                                                  float* __restrict__ part,
                                                  float* __restrict__ stats) {
    constexpr int BK = 64;
    constexpr float SCALE = 0.022097086912079608f;   // 1/sqrt(2048)

    __shared__ __align__(16) char smem[65536];
    unsigned short* As = (unsigned short*)smem;             // [2][8192] QK staging
    unsigned short* Bs = (unsigned short*)(smem + 32768);   // [2][8192]
    unsigned short* Ps = (unsigned short*)smem;             // [128][136] P~ (overlay, post-QK)
    unsigned short* Vs = (unsigned short*)(smem + 34816);   // [64][136]  V chunk
    float* smax = (float*)(smem + 52224);                   // [128][2]
    float* ssum = (float*)(smem + 53248);                   // [128][2]

    // rectangular causal fold
    int T2 = (int)gridDim.y * 2;
    int xx = blockIdx.x, rr = blockIdx.y;
    int bx, by;
    if (xx <= rr) { by = rr; bx = xx; }
    else          { by = T2 - 1 - rr; bx = xx - rr - 1; }
    const int b = blockIdx.z;

    const bf16* A  = qkv + (long long)b * SS * NQKV;         // q rows
    const bf16* Bt = A + DKK;                                // k rows (cols 2048..4095)

    const int tid = threadIdx.x;
    const int lane = tid & 63, wave = tid >> 6;
    const long long m0 = (long long)by * 128;
    const long long n0 = (long long)bx * 128;

    const int rIn = lane >> 3;
    const int cSwz = ((lane & 7) ^ rIn) * 8;
    const int wm0 = (wave >> 1) * 32, wn0 = (wave & 1) * 64;
    const int l15 = lane & 15, quad = lane >> 4;
    const int sw7 = l15 & 7;

    floatx4 acc[2][4] = {};

    auto issue = [&](int buf, int k0) {
        #pragma unroll
        for (int t0 = 0; t0 < 4; ++t0) {
            int t = t0 * 8 + wave;
            if (t < 16)
                async_copy16(A + (m0 + t * 8 + rIn) * (long long)NQKV + k0 + cSwz,
                             &As[buf * 8192 + t * 512]);
            else
                async_copy16(Bt + (n0 + (t - 16) * 8 + rIn) * (long long)NQKV + k0 + cSwz,
                             &Bs[buf * 8192 + (t - 16) * 512]);
        }
    };

    issue(0, 0);
    __syncthreads();
    for (int it = 0; it < DKK / BK; ++it) {
        const int cur = it & 1;
        if (it + 1 < DKK / BK) issue(cur ^ 1, (it + 1) * BK);
        #pragma unroll
        for (int sk = 0; sk < 2; ++sk) {
            const int rchunk = ((sk << 2) | quad) ^ sw7;
            bf16x8 af[2], bfr[4];
            #pragma unroll
            for (int mi = 0; mi < 2; ++mi)
                af[mi] = *reinterpret_cast<const bf16x8*>(
                    &As[cur * 8192 + (wm0 + mi * 16 + l15) * BK + rchunk * 8]);
            #pragma unroll
            for (int ni = 0; ni < 4; ++ni)
                bfr[ni] = *reinterpret_cast<const bf16x8*>(
                    &Bs[cur * 8192 + (wn0 + ni * 16 + l15) * BK + rchunk * 8]);
            #pragma unroll
            for (int mi = 0; mi < 2; ++mi)
                #pragma unroll
                for (int ni = 0; ni < 4; ++ni)
                    acc[mi][ni] = __builtin_amdgcn_mfma_f32_16x16x32_bf16(af[mi], bfr[ni],
                                                                          acc[mi][ni], 0, 0, 0);
        }
        __syncthreads();
    }
    // QK done; staging LDS dead. S (scaled) in acc, C-layout: row=wm0+mi*16+quad*4+r, col=wn0+ni*16+l15.

    // scale + causal mask (diagonal tile only)
    #pragma unroll
    for (int mi = 0; mi < 2; ++mi)
        #pragma unroll
        for (int ni = 0; ni < 4; ++ni)
            #pragma unroll
            for (int r = 0; r < 4; ++r) {
                float v = acc[mi][ni][r] * SCALE;
                if (bx == by) {
                    int row = wm0 + mi * 16 + quad * 4 + r;
                    int col = wn0 + ni * 16 + l15;
                    if (col > row) v = -INFINITY;
                }
                acc[mi][ni][r] = v;
            }

    // row max within tile: over ni in-reg, over l15 via shfl, over wave-halves via LDS
    float rmax[2][4];
    #pragma unroll
    for (int mi = 0; mi < 2; ++mi)
        #pragma unroll
        for (int r = 0; r < 4; ++r) {
            float m = fmaxf(fmaxf(acc[mi][0][r], acc[mi][1][r]),
                            fmaxf(acc[mi][2][r], acc[mi][3][r]));
            #pragma unroll
            for (int msk = 8; msk >= 1; msk >>= 1) m = fmaxf(m, __shfl_xor(m, msk));
            rmax[mi][r] = m;
            if (l15 == 0) smax[(wm0 + mi * 16 + quad * 4 + r) * 2 + (wave & 1)] = m;
        }
    __syncthreads();
    #pragma unroll
    for (int mi = 0; mi < 2; ++mi)
        #pragma unroll
        for (int r = 0; r < 4; ++r) {
            int row = wm0 + mi * 16 + quad * 4 + r;
            rmax[mi][r] = fmaxf(smax[row * 2], smax[row * 2 + 1]);
        }

    // exp + row sums (half-tile); write P~ to padded LDS
    #pragma unroll
    for (int mi = 0; mi < 2; ++mi)
        #pragma unroll
        for (int r = 0; r < 4; ++r) {
            float s = 0.f;
            #pragma unroll
            for (int ni = 0; ni < 4; ++ni) {
                float p = __expf(acc[mi][ni][r] - rmax[mi][r]);   // exp(-inf)=0 for masked
                acc[mi][ni][r] = p;
                s += p;
            }
            #pragma unroll
            for (int msk = 8; msk >= 1; msk >>= 1) s += __shfl_xor(s, msk);
            if (l15 == 0) ssum[(wm0 + mi * 16 + quad * 4 + r) * 2 + (wave & 1)] = s;
        }
    #pragma unroll
    for (int mi = 0; mi < 2; ++mi) {
        int row = wm0 + mi * 16 + quad * 4;
        #pragma unroll
        for (int ni = 0; ni < 4; ++ni) {
            int col = wn0 + ni * 16 + l15;
            #pragma unroll
            for (int r = 0; r < 4; ++r)
                Ps[(row + r) * 136 + col] = (unsigned short)__bfloat16_as_ushort(__float2bfloat16(acc[mi][ni][r]));
        }
    }

    // stage V chunk: Vs[j][k] = vt[b][j][n0+k], xor-swizzled 16B chunks
    #pragma unroll
    for (int p = 0; p < 2; ++p) {
        int j = (tid >> 4) + p * 32;          // 0..63 dvv
        int ch = tid & 15;                    // 16 chunks of 8 bf16
        uint4 v = *reinterpret_cast<const uint4*>(
            vt + ((long long)b * DVV + j) * SS + n0 + ch * 8);
        *reinterpret_cast<uint4*>(&Vs[j * 136 + ((ch ^ (j & 7)) * 8)]) = v;
    }
    __syncthreads();

    // per-row stats out (m, l)
    if (tid < 128) {
        float m = fmaxf(smax[tid * 2], smax[tid * 2 + 1]);
        float l = ssum[tid * 2] + ssum[tid * 2 + 1];
        long long o = (((long long)b * 16 + bx) * SS + m0 + tid) * 2;
        stats[o] = m;
        stats[o + 1] = l;
    }

    // O' = P~ . V  (M=128, N=64, K=128): wave-tile 16 rows x 64 cols
    const int wmv = wave * 16;
    floatx4 accO[4] = {};
    #pragma unroll
    for (int sk = 0; sk < 4; ++sk) {
        bf16x8 af = *reinterpret_cast<const bf16x8*>(
            &Ps[(wmv + l15) * 136 + sk * 32 + quad * 8]);
        #pragma unroll
        for (int ni = 0; ni < 4; ++ni) {
            bf16x8 bfv = *reinterpret_cast<const bf16x8*>(
                &Vs[(ni * 16 + l15) * 136 + ((((sk << 2) | quad)) ^ sw7) * 8]);
            accO[ni] = __builtin_amdgcn_mfma_f32_16x16x32_bf16(af, bfv, accO[ni], 0, 0, 0);
        }
    }
    #pragma unroll
    for (int ni = 0; ni < 4; ++ni)
        #pragma unroll
        for (int r = 0; r < 4; ++r)
            part[(((long long)b * 16 + bx) * SS + m0 + wmv + quad * 4 + r) * 64 + ni * 16 + l15]
                = accO[ni][r];
}

// ---------------- combine k-tile partials: out = sum_t e^{m_t-M} O'_t / sum_t e^{m_t-M} l_t ----
__global__ __launch_bounds__(256) void combine(const float* __restrict__ part,
                                               const float* __restrict__ stats,
                                               float* __restrict__ out) {
    int i = blockIdx.x * 256 + threadIdx.x;   // over 8192*64
    int col = i & 63;
    int row = i >> 6;
    int b = row >> 11, s = row & (SS - 1);
    int nt = (s >> 7) + 1;                    // live k-tiles for this row
    float m[16], l[16], M = -INFINITY;
    #pragma unroll
    for (int t = 0; t < 16; ++t)
        if (t < nt) {
            long long o = (((long long)b * 16 + t) * SS + s) * 2;
            m[t] = stats[o];
            l[t] = stats[o + 1];
            M = fmaxf(M, m[t]);
        }
    float O = 0.f, L = 0.f;
    #pragma unroll
    for (int t = 0; t < 16; ++t)
        if (t < nt) {
            float wgt = __expf(m[t] - M);
            L += wgt * l[t];
            O += wgt * part[(((long long)b * 16 + t) * SS + s) * 64 + col];
        }
    out[i] = O / L;
}

extern "C" void kernel_launch(void* const* d_in, const int* in_sizes, int n_in,
                              void* d_out, int out_size, void* d_ws, size_t ws_size,
                              hipStream_t stream) {
    const float* x  = (const float*)d_in[0];
    const float* Wq = (const float*)d_in[1];
    const float* Wk = (const float*)d_in[2];
    const float* Wv = (const float*)d_in[3];
    float* out = (float*)d_out;

    char* w = (char*)d_ws;
    bf16* xb  = (bf16*)(w + XB_OFF);
    bf16* wt  = (bf16*)(w + WT_OFF);
    bf16* vt  = (bf16*)(w + VT_OFF);
    bf16* qkv = (bf16*)(w + QK_OFF);
    float* part  = (float*)(w + SC_OFF);   // [4][16][2048][64] fp32 (same bytes as old scores)
    float* stats = (float*)(w + WT_OFF);   // alias: wt dead after projection

    // 1. conversions / transposes
    convert_x<<<ROWS * DIN / 4 / 256, 256, 0, stream>>>(x, xb, ROWS * DIN / 4);
    transpose_w<<<dim3(NQKV / 32, DIN / 32), 256, 0, stream>>>(Wq, Wk, Wv, wt);

    // 2. fused q|k|v projection
    gemm_db8<bf16><<<dim3(NQKV / 128, ROWS / 128, 1), 512, 0, stream>>>(
        xb, wt, qkv, DIN, DIN, DIN, NQKV);

    // 2b. vt from qkv v-columns
    transpose_v<<<ROWS / 64, 256, 0, stream>>>(qkv, vt);

    // 3. fused attention tiles (QK^T + per-tile softmax + P~V), rectangular causal fold
    attn_fused<<<dim3(SS / 128 + 1, SS / 256, BB), 512, 0, stream>>>(qkv, vt, part, stats);

    // 4. combine partials -> out
    combine<<<ROWS * DVV / 256, 256, 0, stream>>>(part, stats, out);
}